// Round 4
// baseline (175.970 us; speedup 1.0000x reference)
//
#include <hip/hip_runtime.h>

// ---- ws layout (float offsets) ----
constexpr int F_ELEMS = 4 * 32 * 4 * 48;            // padded-48 conv1 tables
constexpr int PREDS_OFF = F_ELEMS;                  // 24576
constexpr int RBCP_OFF = PREDS_OFF + 1024 * 256;    // rbc_part[64][32]
constexpr int CNT_OFF = RBCP_OFF + 2048;            // completion counter (+pad)
constexpr int W1P_OFF = CNT_OFF + 16;               // fc1 A-frags: 4096 shorts = 2048 f
constexpr int W2P_OFF = W1P_OFF + 2048;             // fc2 A-frags: 32768 shorts = 16384 f
constexpr int W3P_OFF = W2P_OFF + 16384;            // fc3 A-frags: 32768 shorts

typedef __attribute__((ext_vector_type(8))) short short8;
typedef __attribute__((ext_vector_type(4))) short short4v;
typedef __attribute__((ext_vector_type(4))) float f32x4;

__device__ __forceinline__ unsigned short f2bf(float x) {  // RNE bf16
    unsigned u = __float_as_uint(x);
    u += 0x7FFF + ((u >> 16) & 1);
    return (unsigned short)(u >> 16);
}

// quad_perm DPP: lane -> lane^m within each 4-lane quad (VALU, no LDS pipe).
// r3 A/B vs __shfl_xor: NEUTRAL (bank conflicts 1.65M unchanged -> conflicts are
// MFMA-phase ds ops, not shuffles). Kept: marginally fewer LDS-pipe ops.
template <int CTRL>
__device__ __forceinline__ float qp(float x) {
    return __int_as_float(__builtin_amdgcn_update_dpp(
        0, __float_as_int(x), CTRL, 0xF, 0xF, true));
}

// ---------------- Kernel 0: all preprocessing (single-bf16 weights) ----------------
// b<96: F tables. b<112: W1p (4096). b<240: W2p (32768). b<368: W3p (32768). b==368: zero.
__global__ void prep_all(const float* __restrict__ emb, const float* __restrict__ w1,
                         const float* __restrict__ fc1_w, const float* __restrict__ fc2_w,
                         const float* __restrict__ fc3_w,
                         float* __restrict__ F, unsigned short* __restrict__ W1p,
                         unsigned short* __restrict__ W2p, unsigned short* __restrict__ W3p,
                         float* __restrict__ rbcp_zero) {
    int b = blockIdx.x;
    if (b < 96) {
        int idx = b * 256 + threadIdx.x;  // 24576
        int i = idx % 48;
        int o = (idx / 48) % 4;
        int node = (idx / 192) % 32;
        int c = idx / 6144;
        float acc = 0.f;
        if (i < 46) {
#pragma unroll
            for (int k = 0; k < 3; k++) acc += w1[(o * 4 + c) * 3 + k] * emb[node * 96 + 2 * i + k];
        }
        F[idx] = acc;
        return;
    }
    if (b < 112) {  // fc1 A-layout, K padded 16->32, single bf16
        int t = (b - 96) * 256 + threadIdx.x;  // 4096
        int j = t & 7, lane = (t >> 3) & 63, mt = t >> 9;
        int k = (lane >> 4) * 8 + j, n = mt * 16 + (lane & 15);
        float w = (k < 16) ? fc1_w[k * 128 + n] : 0.f;
        W1p[t] = f2bf(w);
        return;
    }
    if (b < 240) {  // fc2 A-layout [16mt][4ks], single bf16
        int t = (b - 112) * 256 + threadIdx.x;  // 32768
        int j = t & 7, lane = (t >> 3) & 63, ks = (t >> 9) & 3, mt = t >> 11;
        int k = ks * 32 + (lane >> 4) * 8 + j, n = mt * 16 + (lane & 15);
        W2p[t] = f2bf(fc2_w[k * 256 + n]);
        return;
    }
    if (b < 368) {  // fc3 A-layout [8mt][8ks], single bf16
        int t = (b - 240) * 256 + threadIdx.x;  // 32768
        int j = t & 7, lane = (t >> 3) & 63, ks = (t >> 9) & 7, mt = t >> 12;
        int k = ks * 32 + (lane >> 4) * 8 + j, n = mt * 16 + (lane & 15);
        W3p[t] = f2bf(fc3_w[k * 128 + n]);
        return;
    }
    for (int k = threadIdx.x; k < 2064; k += 256) rbcp_zero[k] = 0.f;  // rbc_part + counter
}

// ---------------- Kernel 1: fc2/fc3 in FOUR 64-col quarters -> LDS 24576 B -> 6 blocks/CU.
// Established dead ends (do not retry): multi-chunk loop (r10: spills), min-waves=6
// (r12: VGPR clamp+spill), 64-wide quarters of samples (r14: flat), fused prop (r8: +19us),
// one-block-per-pair (r10), DPP-for-shfl (r3: neutral). ----------------
__global__ __launch_bounds__(256, 4)
void mlp_kernel(const float* __restrict__ F, const int* __restrict__ edges,
                const float* __restrict__ b1v,
                const float* __restrict__ w2, const float* __restrict__ b2,
                const float* __restrict__ w3, const float* __restrict__ b3,
                const float* __restrict__ fc1_b, const float* __restrict__ fc2_b,
                const float* __restrict__ fc3_b,
                const float* __restrict__ fc4_w, const float* __restrict__ fc4_b,
                const unsigned short* __restrict__ W1p, const unsigned short* __restrict__ W2p,
                const unsigned short* __restrict__ W3p,
                float* __restrict__ preds) {
    // LDS (floats): [0,2048) X3-quarter region (X1 aliases its head);
    //               [2048,6144) X2 (part[256] aliases X2 head after last X2 read)
    __shared__ __align__(16) float smem[6144];
    unsigned short* X1 = (unsigned short*)smem;
    unsigned short* X3q = (unsigned short*)smem;
    unsigned short* X2 = (unsigned short*)(smem + 2048);
    float* part = smem + 2048;  // aliases X2 head; write is 2 barriers after last X2 read

    const int tid = threadIdx.x;
    const int p = blockIdx.x >> 2;
    const int e0 = (blockIdx.x & 3) * 64;
    const int s = p >> 5, t = p & 31;
    if (s == t) return;

    const int gsample = tid >> 2, o = tid & 3;  // conv roles
    float h1[23];
    // ---- conv1: table sum (float4 loads, padded-48 rows) + pool -> regs ----
    {
        const int e = e0 + gsample;
        const int u = edges[2 * e], v = edges[2 * e + 1];
        const f32x4* F0 = (const f32x4*)(F + ((0 * 32 + s) * 4 + o) * 48);
        const f32x4* F1 = (const f32x4*)(F + ((1 * 32 + t) * 4 + o) * 48);
        const f32x4* F2 = (const f32x4*)(F + ((2 * 32 + u) * 4 + o) * 48);
        const f32x4* F3 = (const f32x4*)(F + ((3 * 32 + v) * 4 + o) * 48);
        const float bb = b1v[o];
        float pre[46];
#pragma unroll
        for (int q = 0; q < 12; q++) {
            f32x4 x = F0[q] + F1[q] + F2[q] + F3[q];
#pragma unroll
            for (int z = 0; z < 4; z++) {
                int i = 4 * q + z;
                if (i < 46) pre[i] = fmaxf(x[z] + bb, 0.f);
            }
        }
#pragma unroll
        for (int j = 0; j < 23; j++) h1[j] = fmaxf(pre[2 * j], pre[2 * j + 1]);
    }
    float h2[10];
    // ---- conv2: cross-channel via DPP quad_perm (4-lane groups), sliding ring ----
    {
        float wm[4][3];  // wm[m][k] = w2[o][o^m][k]
#pragma unroll
        for (int m = 0; m < 4; m++)
#pragma unroll
            for (int k = 0; k < 3; k++) wm[m][k] = w2[o * 12 + (o ^ m) * 3 + k];
        const float bb = b2[o];
        float win[4][3];
#pragma unroll
        for (int j = 0; j < 2; j++) {
            float x = h1[j];
            win[0][j] = x;
            win[1][j] = qp<0xB1>(x);
            win[2][j] = qp<0x4E>(x);
            win[3][j] = qp<0x1B>(x);
        }
        float pre[20];
#pragma unroll
        for (int i = 0; i < 20; i++) {
            float x = h1[i + 2];
            win[0][(i + 2) % 3] = x;
            win[1][(i + 2) % 3] = qp<0xB1>(x);
            win[2][(i + 2) % 3] = qp<0x4E>(x);
            win[3][(i + 2) % 3] = qp<0x1B>(x);
            float acc = bb;
#pragma unroll
            for (int m = 0; m < 4; m++)
#pragma unroll
                for (int k = 0; k < 3; k++)
                    acc = fmaf(wm[m][k], win[m][(i + k) % 3], acc);
            pre[i] = fmaxf(acc, 0.f);
        }
#pragma unroll
        for (int j = 0; j < 10; j++) h2[j] = fmaxf(pre[2 * j], pre[2 * j + 1]);
    }
    // ---- conv3 + pool -> X1 (bf16 B-frag layout, K 16 padded to 32) ----
    {
        float wm[4][3];
#pragma unroll
        for (int m = 0; m < 4; m++)
#pragma unroll
            for (int k = 0; k < 3; k++) wm[m][k] = w3[o * 12 + (o ^ m) * 3 + k];
        const float bb = b3[o];
        float win[4][3];
#pragma unroll
        for (int j = 0; j < 2; j++) {
            float x = h2[j];
            win[0][j] = x;
            win[1][j] = qp<0xB1>(x);
            win[2][j] = qp<0x4E>(x);
            win[3][j] = qp<0x1B>(x);
        }
        float pre[8];
#pragma unroll
        for (int i = 0; i < 8; i++) {
            float x = h2[i + 2];
            win[0][(i + 2) % 3] = x;
            win[1][(i + 2) % 3] = qp<0xB1>(x);
            win[2][(i + 2) % 3] = qp<0x4E>(x);
            win[3][(i + 2) % 3] = qp<0x1B>(x);
            float acc = bb;
#pragma unroll
            for (int m = 0; m < 4; m++)
#pragma unroll
                for (int k = 0; k < 3; k++)
                    acc = fmaf(wm[m][k], win[m][(i + k) % 3], acc);
            pre[i] = fmaxf(acc, 0.f);
        }
        short4v pk;
#pragma unroll
        for (int l = 0; l < 4; l++)
            pk[l] = (short)f2bf(fmaxf(pre[2 * l], pre[2 * l + 1]));
        *(short4v*)(X1 + (((o >> 1) * 64 + gsample) * 8) + (o & 1) * 4) = pk;
        short4v z4 = (short4v){0, 0, 0, 0};  // k in [16,32) zeros
        *(short4v*)(X1 + ((((o >> 1) + 2) * 64 + gsample) * 8) + (o & 1) * 4) = z4;
    }
    __syncthreads();  // barrier 1: X1 visible to all waves
    const int lane = tid & 63, wave = tid >> 6;
    const int mrow = lane & 15, quad = lane >> 4;
    // ---- fc1 MFMA: A=W1p (8 mt, wave owns 2), B=X1 ----
    {
        const short8* W1v = (const short8*)W1p;
        short8 bnt[4];
#pragma unroll
        for (int nt = 0; nt < 4; nt++)
            bnt[nt] = *(const short8*)(X1 + (quad * 64 + nt * 16 + mrow) * 8);
        f32x4 acc1[2][4];
#pragma unroll
        for (int a = 0; a < 2; a++)
#pragma unroll
            for (int b = 0; b < 4; b++) acc1[a][b] = (f32x4){0.f, 0.f, 0.f, 0.f};
#pragma unroll
        for (int mtl = 0; mtl < 2; mtl++) {
            const int mt = wave * 2 + mtl;
            short8 ah = W1v[mt * 64 + lane];
#pragma unroll
            for (int nt = 0; nt < 4; nt++)
                acc1[mtl][nt] = __builtin_amdgcn_mfma_f32_16x16x32_bf16(ah, bnt[nt], acc1[mtl][nt], 0, 0, 0);
        }
        // epilogue straight to X2 (disjoint region; no barrier needed)
#pragma unroll
        for (int mtl = 0; mtl < 2; mtl++) {
            const int mt = wave * 2 + mtl;
            const int n0 = mt * 16 + quad * 4;
            f32x4 b4 = *(const f32x4*)(fc1_b + n0);
#pragma unroll
            for (int nt = 0; nt < 4; nt++) {
                short4v pk;
#pragma unroll
                for (int r = 0; r < 4; r++)
                    pk[r] = (short)f2bf(fmaxf(acc1[mtl][nt][r] + b4[r], 0.f));
                *(short4v*)(X2 + ((n0 >> 3) * 64 + nt * 16 + mrow) * 8 + (n0 & 7)) = pk;
            }
        }
    }
    __syncthreads();  // barrier 2: X2 visible; X1 reads done (X3q writes may follow)
    // ---- fc2 -> fc3 in FOUR K=64 quarters through X3q (8 KB) ----
    const short8* W2v = (const short8*)W2p;
    const short8* W3v = (const short8*)W3p;
    f32x4 acc3[2][4];
#pragma unroll
    for (int a = 0; a < 2; a++)
#pragma unroll
        for (int b = 0; b < 4; b++) acc3[a][b] = (f32x4){0.f, 0.f, 0.f, 0.f};
#pragma unroll
    for (int q = 0; q < 4; q++) {
        // fc2 quarter: wave owns 1 of 4 mt in this quarter (full K=128 from X2)
        const int mt2 = q * 4 + wave;
        f32x4 acc2[4];
#pragma unroll
        for (int b = 0; b < 4; b++) acc2[b] = (f32x4){0.f, 0.f, 0.f, 0.f};
#pragma unroll
        for (int ks = 0; ks < 4; ks++) {
            short8 bfr[4];
#pragma unroll
            for (int nt = 0; nt < 4; nt++)
                bfr[nt] = *(const short8*)(X2 + ((ks * 4 + quad) * 64 + nt * 16 + mrow) * 8);
            short8 ah = W2v[(mt2 * 4 + ks) * 64 + lane];
#pragma unroll
            for (int nt = 0; nt < 4; nt++)
                acc2[nt] = __builtin_amdgcn_mfma_f32_16x16x32_bf16(ah, bfr[nt], acc2[nt], 0, 0, 0);
        }
        // epilogue -> X3q (k-local = n - q*64, in [0,64))
        {
            const int n0 = mt2 * 16 + quad * 4;
            const int kl = n0 - q * 64;
            f32x4 b4 = *(const f32x4*)(fc2_b + n0);
#pragma unroll
            for (int nt = 0; nt < 4; nt++) {
                short4v pk;
#pragma unroll
                for (int r = 0; r < 4; r++)
                    pk[r] = (short)f2bf(fmaxf(acc2[nt][r] + b4[r], 0.f));
                *(short4v*)(X3q + ((kl >> 3) * 64 + nt * 16 + mrow) * 8 + (kl & 7)) = pk;
            }
        }
        __syncthreads();  // X3q quarter ready
        // fc3 accumulate this quarter's 2 ks
#pragma unroll
        for (int ksl = 0; ksl < 2; ksl++) {
            const int ks = q * 2 + ksl;
            short8 bfr[4];
#pragma unroll
            for (int nt = 0; nt < 4; nt++)
                bfr[nt] = *(const short8*)(X3q + ((ksl * 4 + quad) * 64 + nt * 16 + mrow) * 8);
#pragma unroll
            for (int mtl = 0; mtl < 2; mtl++) {
                const int mt = wave * 2 + mtl;
                short8 ah = W3v[(mt * 8 + ks) * 64 + lane];
#pragma unroll
                for (int nt = 0; nt < 4; nt++)
                    acc3[mtl][nt] = __builtin_amdgcn_mfma_f32_16x16x32_bf16(ah, bfr[nt], acc3[mtl][nt], 0, 0, 0);
            }
        }
        __syncthreads();  // X3q reads done before reuse / part writes
    }
    // ---- fused fc4 ----
    {
        float p4[4] = {0.f, 0.f, 0.f, 0.f};
#pragma unroll
        for (int mtl = 0; mtl < 2; mtl++) {
            const int mt = wave * 2 + mtl;
            const int n0 = mt * 16 + quad * 4;
            f32x4 b4 = *(const f32x4*)(fc3_b + n0);
            f32x4 w44 = *(const f32x4*)(fc4_w + n0);
#pragma unroll
            for (int nt = 0; nt < 4; nt++)
#pragma unroll
                for (int r = 0; r < 4; r++)
                    p4[nt] = fmaf(fmaxf(acc3[mtl][nt][r] + b4[r], 0.f), w44[r], p4[nt]);
        }
#pragma unroll
        for (int nt = 0; nt < 4; nt++) {
            p4[nt] += __shfl_xor(p4[nt], 16, 64);
            p4[nt] += __shfl_xor(p4[nt], 32, 64);
        }
        if (quad == 0) {
#pragma unroll
            for (int nt = 0; nt < 4; nt++)
                part[wave * 64 + nt * 16 + mrow] = p4[nt];
        }
    }
    __syncthreads();
    if (tid < 64) {
        float pred = part[tid] + part[64 + tid] + part[128 + tid] + part[192 + tid] + fc4_b[0];
        preds[p * 256 + e0 + tid] = pred;
    }
}

// ---------------- Kernel 2: propagation, one WAVE per pair (256 blocks) + fused normalize ----------------
__global__ __launch_bounds__(256)
void prop_norm(const int* __restrict__ edges, const float* __restrict__ preds,
               float* __restrict__ rbc_part, int* __restrict__ counter,
               float* __restrict__ out) {
    const int tid = threadIdx.x;
    const int wave = tid >> 6, lane = tid & 63;
    const int p = blockIdx.x * 4 + wave;
    const int s = p >> 5, t = p & 31;
    __shared__ float xw[4][32], xnw[4][32], raccw[4][32];
    __shared__ float red[8][32];
    __shared__ int lastflag;
    int u[4], v[4];
    float pr[4];
#pragma unroll
    for (int j = 0; j < 4; j++) {
        int e = lane + 64 * j;
        u[j] = edges[2 * e];
        v[j] = edges[2 * e + 1];
        pr[j] = preds[p * 256 + e];
    }
    if (lane < 32) { xw[wave][lane] = (lane == s) ? 1.f : 0.f; raccw[wave][lane] = 0.f; }
    const bool active = (s != t);
    for (int step = 0; step < 3; step++) {
        if (lane < 32) xnw[wave][lane] = 0.f;
        __syncthreads();
        if (active) {
#pragma unroll
            for (int j = 0; j < 4; j++)
                atomicAdd(&xnw[wave][v[j]], xw[wave][u[j]] * pr[j]);
        }
        __syncthreads();
        if (lane < 32) { raccw[wave][lane] += xnw[wave][lane]; xw[wave][lane] = xnw[wave][lane]; }
        __syncthreads();
    }
    if (active && lane < 32) atomicAdd(&rbc_part[(p & 63) * 32 + lane], raccw[wave][lane]);
    __syncthreads();  // drains rbc_part atomics before counter bump
    if (tid == 0) lastflag = (atomicAdd(counter, 1) == 255);
    __syncthreads();
    if (!lastflag) return;
    const int node = tid & 31, sub = tid >> 5;
    float vv = 0.f;
#pragma unroll
    for (int g = 0; g < 8; g++)
        vv += atomicAdd(&rbc_part[(sub * 8 + g) * 32 + node], 0.f);  // coherent read
    red[sub][node] = vv;
    __syncthreads();
    if (tid < 32) {
        float acc = 0.f;
#pragma unroll
        for (int sb = 0; sb < 8; sb++) acc += red[sb][tid];
        float tot = acc;
#pragma unroll
        for (int mask = 1; mask < 32; mask <<= 1) tot += __shfl_xor(tot, mask, 32);
        out[tid] = acc / tot;
    }
}

extern "C" void kernel_launch(void* const* d_in, const int* in_sizes, int n_in,
                              void* d_out, int out_size, void* d_ws, size_t ws_size,
                              hipStream_t stream) {
    const float* emb = (const float*)d_in[0];
    const int* edges = (const int*)d_in[1];
    const float* w1 = (const float*)d_in[2];
    const float* b1 = (const float*)d_in[3];
    const float* w2 = (const float*)d_in[4];
    const float* b2 = (const float*)d_in[5];
    const float* w3 = (const float*)d_in[6];
    const float* b3 = (const float*)d_in[7];
    const float* fc1_w = (const float*)d_in[8];
    const float* fc1_b = (const float*)d_in[9];
    const float* fc2_w = (const float*)d_in[10];
    const float* fc2_b = (const float*)d_in[11];
    const float* fc3_w = (const float*)d_in[12];
    const float* fc3_b = (const float*)d_in[13];
    const float* fc4_w = (const float*)d_in[14];
    const float* fc4_b = (const float*)d_in[15];

    float* ws = (float*)d_ws;
    float* F = ws;
    float* preds = ws + PREDS_OFF;
    float* rbc_part = ws + RBCP_OFF;
    int* counter = (int*)(ws + CNT_OFF);
    unsigned short* W1p = (unsigned short*)(ws + W1P_OFF);
    unsigned short* W2p = (unsigned short*)(ws + W2P_OFF);
    unsigned short* W3p = (unsigned short*)(ws + W3P_OFF);
    float* out = (float*)d_out;

    prep_all<<<dim3(369), dim3(256), 0, stream>>>(emb, w1, fc1_w, fc2_w, fc3_w,
                                                  F, W1p, W2p, W3p, rbc_part);
    mlp_kernel<<<dim3(4096), dim3(256), 0, stream>>>(
        F, edges, b1, w2, b2, w3, b3, fc1_b, fc2_b, fc3_b,
        fc4_w, fc4_b, W1p, W2p, W3p, preds);
    prop_norm<<<dim3(256), dim3(256), 0, stream>>>(edges, preds, rbc_part, counter, out);
}

// Round 5
// 167.491 us; speedup vs baseline: 1.0506x; 1.0506x over previous
//
#include <hip/hip_runtime.h>

// ---- ws layout (float offsets) ----
constexpr int F_ELEMS = 4 * 32 * 4 * 48;            // padded-48 conv1 tables
constexpr int PREDS_OFF = F_ELEMS;                  // 24576
constexpr int RBCP_OFF = PREDS_OFF + 1024 * 256;    // rbc_part[64][32]
constexpr int CNT_OFF = RBCP_OFF + 2048;            // completion counter (+pad)
constexpr int W1P_OFF = CNT_OFF + 16;               // fc1 A-frags: 4096 shorts = 2048 f
constexpr int W2P_OFF = W1P_OFF + 2048;             // fc2 A-frags: 32768 shorts = 16384 f
constexpr int W3P_OFF = W2P_OFF + 16384;            // fc3 A-frags: 32768 shorts

typedef __attribute__((ext_vector_type(8))) short short8;
typedef __attribute__((ext_vector_type(4))) short short4v;
typedef __attribute__((ext_vector_type(4))) float f32x4;
typedef __attribute__((ext_vector_type(2))) unsigned int uint2v;

__device__ __forceinline__ unsigned short f2bf(float x) {  // RNE bf16 (prep only)
    unsigned u = __float_as_uint(x);
    u += 0x7FFF + ((u >> 16) & 1);
    return (unsigned short)(u >> 16);
}

// One-instruction packed f32->bf16 pair (low = a, high = b). Replaces ~12-op
// hand-rolled RNE + pack per pair in the hot epilogues.
__device__ __forceinline__ unsigned cvt_pk_bf16(float a, float b) {
    unsigned r;
    asm("v_cvt_pk_bf16_f32 %0, %1, %2" : "=v"(r) : "v"(a), "v"(b));
    return r;
}

// quad_perm DPP: lane -> lane^m within each 4-lane quad (VALU, no LDS pipe).
// r3 A/B vs __shfl_xor: NEUTRAL. Kept: fewer LDS-pipe ops.
template <int CTRL>
__device__ __forceinline__ float qp(float x) {
    return __int_as_float(__builtin_amdgcn_update_dpp(
        0, __float_as_int(x), CTRL, 0xF, 0xF, true));
}

// ---------------- Kernel 0: all preprocessing (single-bf16 weights) ----------------
// b<96: F tables. b<112: W1p (4096). b<240: W2p (32768). b<368: W3p (32768). b==368: zero.
__global__ void prep_all(const float* __restrict__ emb, const float* __restrict__ w1,
                         const float* __restrict__ fc1_w, const float* __restrict__ fc2_w,
                         const float* __restrict__ fc3_w,
                         float* __restrict__ F, unsigned short* __restrict__ W1p,
                         unsigned short* __restrict__ W2p, unsigned short* __restrict__ W3p,
                         float* __restrict__ rbcp_zero) {
    int b = blockIdx.x;
    if (b < 96) {
        int idx = b * 256 + threadIdx.x;  // 24576
        int i = idx % 48;
        int o = (idx / 48) % 4;
        int node = (idx / 192) % 32;
        int c = idx / 6144;
        float acc = 0.f;
        if (i < 46) {
#pragma unroll
            for (int k = 0; k < 3; k++) acc += w1[(o * 4 + c) * 3 + k] * emb[node * 96 + 2 * i + k];
        }
        F[idx] = acc;
        return;
    }
    if (b < 112) {  // fc1 A-layout, K padded 16->32, single bf16
        int t = (b - 96) * 256 + threadIdx.x;  // 4096
        int j = t & 7, lane = (t >> 3) & 63, mt = t >> 9;
        int k = (lane >> 4) * 8 + j, n = mt * 16 + (lane & 15);
        float w = (k < 16) ? fc1_w[k * 128 + n] : 0.f;
        W1p[t] = f2bf(w);
        return;
    }
    if (b < 240) {  // fc2 A-layout [16mt][4ks], single bf16
        int t = (b - 112) * 256 + threadIdx.x;  // 32768
        int j = t & 7, lane = (t >> 3) & 63, ks = (t >> 9) & 3, mt = t >> 11;
        int k = ks * 32 + (lane >> 4) * 8 + j, n = mt * 16 + (lane & 15);
        W2p[t] = f2bf(fc2_w[k * 256 + n]);
        return;
    }
    if (b < 368) {  // fc3 A-layout [8mt][8ks], single bf16
        int t = (b - 240) * 256 + threadIdx.x;  // 32768
        int j = t & 7, lane = (t >> 3) & 63, ks = (t >> 9) & 7, mt = t >> 12;
        int k = ks * 32 + (lane >> 4) * 8 + j, n = mt * 16 + (lane & 15);
        W3p[t] = f2bf(fc3_w[k * 128 + n]);
        return;
    }
    for (int k = threadIdx.x; k < 2064; k += 256) rbcp_zero[k] = 0.f;  // rbc_part + counter
}

// ---------------- Kernel 1: r3 two-half structure + cvt_pk epilogues + pool-before-relu.
// Established dead ends (do not retry): multi-chunk loop (spills), min-waves=6
// (VGPR clamp+spill), 64-wide sample quarters (flat), fused prop (+19us),
// one-block-per-pair, DPP-for-shfl (r3: neutral, conflicts are MFMA-phase ds ops),
// fc2/fc3 64-col quarters for LDS 24K (r4: occupancy unchanged, +5.5us -> NOT LDS-limited).
__global__ __launch_bounds__(256, 4)
void mlp_kernel(const float* __restrict__ F, const int* __restrict__ edges,
                const float* __restrict__ b1v,
                const float* __restrict__ w2, const float* __restrict__ b2,
                const float* __restrict__ w3, const float* __restrict__ b3,
                const float* __restrict__ fc1_b, const float* __restrict__ fc2_b,
                const float* __restrict__ fc3_b,
                const float* __restrict__ fc4_w, const float* __restrict__ fc4_b,
                const unsigned short* __restrict__ W1p, const unsigned short* __restrict__ W2p,
                const unsigned short* __restrict__ W3p,
                float* __restrict__ preds) {
    // LDS (floats): [0,4096) X3-half region, X1 aliases its head; [4096,8192) X2; [8192,8448) part
    __shared__ __align__(16) float smem[8448];
    unsigned short* X1 = (unsigned short*)smem;
    unsigned short* X3h = (unsigned short*)smem;
    unsigned short* X2 = (unsigned short*)(smem + 4096);
    float* part = smem + 8192;

    const int tid = threadIdx.x;
    const int p = blockIdx.x >> 2;
    const int e0 = (blockIdx.x & 3) * 64;
    const int s = p >> 5, t = p & 31;
    if (s == t) return;

    const int gsample = tid >> 2, o = tid & 3;  // conv roles
    float h1[23];
    // ---- conv1: table sum (float4 loads, padded-48 rows), pool THEN relu -> regs ----
    {
        const int e = e0 + gsample;
        const int u = edges[2 * e], v = edges[2 * e + 1];
        const f32x4* F0 = (const f32x4*)(F + ((0 * 32 + s) * 4 + o) * 48);
        const f32x4* F1 = (const f32x4*)(F + ((1 * 32 + t) * 4 + o) * 48);
        const f32x4* F2 = (const f32x4*)(F + ((2 * 32 + u) * 4 + o) * 48);
        const f32x4* F3 = (const f32x4*)(F + ((3 * 32 + v) * 4 + o) * 48);
        const float bb = b1v[o];
        float pre[46];
#pragma unroll
        for (int q = 0; q < 12; q++) {
            f32x4 x = F0[q] + F1[q] + F2[q] + F3[q];
#pragma unroll
            for (int z = 0; z < 4; z++) {
                int i = 4 * q + z;
                if (i < 46) pre[i] = x[z] + bb;
            }
        }
#pragma unroll
        for (int j = 0; j < 23; j++) h1[j] = fmaxf(fmaxf(pre[2 * j], pre[2 * j + 1]), 0.f);
    }
    float h2[10];
    // ---- conv2: cross-channel via DPP quad_perm, sliding ring; pool+relu fused ----
    {
        float wm[4][3];  // wm[m][k] = w2[o][o^m][k]
#pragma unroll
        for (int m = 0; m < 4; m++)
#pragma unroll
            for (int k = 0; k < 3; k++) wm[m][k] = w2[o * 12 + (o ^ m) * 3 + k];
        const float bb = b2[o];
        float win[4][3];
#pragma unroll
        for (int j = 0; j < 2; j++) {
            float x = h1[j];
            win[0][j] = x;
            win[1][j] = qp<0xB1>(x);
            win[2][j] = qp<0x4E>(x);
            win[3][j] = qp<0x1B>(x);
        }
        float pre[20];
#pragma unroll
        for (int i = 0; i < 20; i++) {
            float x = h1[i + 2];
            win[0][(i + 2) % 3] = x;
            win[1][(i + 2) % 3] = qp<0xB1>(x);
            win[2][(i + 2) % 3] = qp<0x4E>(x);
            win[3][(i + 2) % 3] = qp<0x1B>(x);
            float acc = bb;
#pragma unroll
            for (int m = 0; m < 4; m++)
#pragma unroll
                for (int k = 0; k < 3; k++)
                    acc = fmaf(wm[m][k], win[m][(i + k) % 3], acc);
            pre[i] = acc;
        }
#pragma unroll
        for (int j = 0; j < 10; j++) h2[j] = fmaxf(fmaxf(pre[2 * j], pre[2 * j + 1]), 0.f);
    }
    // ---- conv3; pool+relu fused; cvt_pk pack -> X1 (bf16 B-frag layout, K 16 pad 32) ----
    {
        float wm[4][3];
#pragma unroll
        for (int m = 0; m < 4; m++)
#pragma unroll
            for (int k = 0; k < 3; k++) wm[m][k] = w3[o * 12 + (o ^ m) * 3 + k];
        const float bb = b3[o];
        float win[4][3];
#pragma unroll
        for (int j = 0; j < 2; j++) {
            float x = h2[j];
            win[0][j] = x;
            win[1][j] = qp<0xB1>(x);
            win[2][j] = qp<0x4E>(x);
            win[3][j] = qp<0x1B>(x);
        }
        float pre[8];
#pragma unroll
        for (int i = 0; i < 8; i++) {
            float x = h2[i + 2];
            win[0][(i + 2) % 3] = x;
            win[1][(i + 2) % 3] = qp<0xB1>(x);
            win[2][(i + 2) % 3] = qp<0x4E>(x);
            win[3][(i + 2) % 3] = qp<0x1B>(x);
            float acc = bb;
#pragma unroll
            for (int m = 0; m < 4; m++)
#pragma unroll
                for (int k = 0; k < 3; k++)
                    acc = fmaf(wm[m][k], win[m][(i + k) % 3], acc);
            pre[i] = acc;
        }
        float v0 = fmaxf(fmaxf(pre[0], pre[1]), 0.f);
        float v1 = fmaxf(fmaxf(pre[2], pre[3]), 0.f);
        float v2 = fmaxf(fmaxf(pre[4], pre[5]), 0.f);
        float v3 = fmaxf(fmaxf(pre[6], pre[7]), 0.f);
        uint2v d;
        d.x = cvt_pk_bf16(v0, v1);
        d.y = cvt_pk_bf16(v2, v3);
        *(uint2v*)(X1 + (((o >> 1) * 64 + gsample) * 8) + (o & 1) * 4) = d;
        uint2v z2 = (uint2v){0u, 0u};  // k in [16,32) zeros
        *(uint2v*)(X1 + ((((o >> 1) + 2) * 64 + gsample) * 8) + (o & 1) * 4) = z2;
    }
    __syncthreads();  // barrier 1: X1 visible to all waves
    const int lane = tid & 63, wave = tid >> 6;
    const int mrow = lane & 15, quad = lane >> 4;
    // ---- fc1 MFMA: A=W1p (8 mt, wave owns 2), B=X1 ----
    {
        const short8* W1v = (const short8*)W1p;
        short8 bnt[4];
#pragma unroll
        for (int nt = 0; nt < 4; nt++)
            bnt[nt] = *(const short8*)(X1 + (quad * 64 + nt * 16 + mrow) * 8);
        f32x4 acc1[2][4];
#pragma unroll
        for (int a = 0; a < 2; a++)
#pragma unroll
            for (int b = 0; b < 4; b++) acc1[a][b] = (f32x4){0.f, 0.f, 0.f, 0.f};
#pragma unroll
        for (int mtl = 0; mtl < 2; mtl++) {
            const int mt = wave * 2 + mtl;
            short8 ah = W1v[mt * 64 + lane];
#pragma unroll
            for (int nt = 0; nt < 4; nt++)
                acc1[mtl][nt] = __builtin_amdgcn_mfma_f32_16x16x32_bf16(ah, bnt[nt], acc1[mtl][nt], 0, 0, 0);
        }
        // epilogue straight to X2 (disjoint region; no barrier needed)
#pragma unroll
        for (int mtl = 0; mtl < 2; mtl++) {
            const int mt = wave * 2 + mtl;
            const int n0 = mt * 16 + quad * 4;
            f32x4 b4 = *(const f32x4*)(fc1_b + n0);
#pragma unroll
            for (int nt = 0; nt < 4; nt++) {
                float x0 = fmaxf(acc1[mtl][nt][0] + b4[0], 0.f);
                float x1 = fmaxf(acc1[mtl][nt][1] + b4[1], 0.f);
                float x2 = fmaxf(acc1[mtl][nt][2] + b4[2], 0.f);
                float x3 = fmaxf(acc1[mtl][nt][3] + b4[3], 0.f);
                uint2v d;
                d.x = cvt_pk_bf16(x0, x1);
                d.y = cvt_pk_bf16(x2, x3);
                *(uint2v*)(X2 + ((n0 >> 3) * 64 + nt * 16 + mrow) * 8 + (n0 & 7)) = d;
            }
        }
    }
    __syncthreads();  // barrier 2: X2 visible; X1 reads done (X3h writes may follow)
    // ---- fc2 -> fc3 in two K=128 halves through X3h ----
    const short8* W2v = (const short8*)W2p;
    const short8* W3v = (const short8*)W3p;
    f32x4 acc3[2][4];
#pragma unroll
    for (int a = 0; a < 2; a++)
#pragma unroll
        for (int b = 0; b < 4; b++) acc3[a][b] = (f32x4){0.f, 0.f, 0.f, 0.f};
#pragma unroll
    for (int h = 0; h < 2; h++) {
        // fc2 half: wave owns 2 of 8 mt in this half (full K=128 from X2)
        f32x4 acc2[2][4];
#pragma unroll
        for (int a = 0; a < 2; a++)
#pragma unroll
            for (int b = 0; b < 4; b++) acc2[a][b] = (f32x4){0.f, 0.f, 0.f, 0.f};
#pragma unroll
        for (int ks = 0; ks < 4; ks++) {
            short8 bfr[4];
#pragma unroll
            for (int nt = 0; nt < 4; nt++)
                bfr[nt] = *(const short8*)(X2 + ((ks * 4 + quad) * 64 + nt * 16 + mrow) * 8);
#pragma unroll
            for (int mtl = 0; mtl < 2; mtl++) {
                const int mt = h * 8 + wave * 2 + mtl;
                short8 ah = W2v[(mt * 4 + ks) * 64 + lane];
#pragma unroll
                for (int nt = 0; nt < 4; nt++)
                    acc2[mtl][nt] = __builtin_amdgcn_mfma_f32_16x16x32_bf16(ah, bfr[nt], acc2[mtl][nt], 0, 0, 0);
            }
        }
        // epilogue -> X3h (k-local = n - h*128)
#pragma unroll
        for (int mtl = 0; mtl < 2; mtl++) {
            const int mt = h * 8 + wave * 2 + mtl;
            const int n0 = mt * 16 + quad * 4;
            const int kl = n0 - h * 128;
            f32x4 b4 = *(const f32x4*)(fc2_b + n0);
#pragma unroll
            for (int nt = 0; nt < 4; nt++) {
                float x0 = fmaxf(acc2[mtl][nt][0] + b4[0], 0.f);
                float x1 = fmaxf(acc2[mtl][nt][1] + b4[1], 0.f);
                float x2 = fmaxf(acc2[mtl][nt][2] + b4[2], 0.f);
                float x3 = fmaxf(acc2[mtl][nt][3] + b4[3], 0.f);
                uint2v d;
                d.x = cvt_pk_bf16(x0, x1);
                d.y = cvt_pk_bf16(x2, x3);
                *(uint2v*)(X3h + ((kl >> 3) * 64 + nt * 16 + mrow) * 8 + (kl & 7)) = d;
            }
        }
        __syncthreads();  // barrier 3/5: X3h half ready
        // fc3 accumulate this half's 4 ks
#pragma unroll
        for (int ksl = 0; ksl < 4; ksl++) {
            const int ks = h * 4 + ksl;
            short8 bfr[4];
#pragma unroll
            for (int nt = 0; nt < 4; nt++)
                bfr[nt] = *(const short8*)(X3h + ((ksl * 4 + quad) * 64 + nt * 16 + mrow) * 8);
#pragma unroll
            for (int mtl = 0; mtl < 2; mtl++) {
                const int mt = wave * 2 + mtl;
                short8 ah = W3v[(mt * 8 + ks) * 64 + lane];
#pragma unroll
                for (int nt = 0; nt < 4; nt++)
                    acc3[mtl][nt] = __builtin_amdgcn_mfma_f32_16x16x32_bf16(ah, bfr[nt], acc3[mtl][nt], 0, 0, 0);
            }
        }
        __syncthreads();  // barrier 4/6: X3h reads done before reuse / part writes
    }
    // ---- fused fc4 ----
    {
        float p4[4] = {0.f, 0.f, 0.f, 0.f};
#pragma unroll
        for (int mtl = 0; mtl < 2; mtl++) {
            const int mt = wave * 2 + mtl;
            const int n0 = mt * 16 + quad * 4;
            f32x4 b4 = *(const f32x4*)(fc3_b + n0);
            f32x4 w44 = *(const f32x4*)(fc4_w + n0);
#pragma unroll
            for (int nt = 0; nt < 4; nt++)
#pragma unroll
                for (int r = 0; r < 4; r++)
                    p4[nt] = fmaf(fmaxf(acc3[mtl][nt][r] + b4[r], 0.f), w44[r], p4[nt]);
        }
#pragma unroll
        for (int nt = 0; nt < 4; nt++) {
            p4[nt] += __shfl_xor(p4[nt], 16, 64);
            p4[nt] += __shfl_xor(p4[nt], 32, 64);
        }
        if (quad == 0) {
#pragma unroll
            for (int nt = 0; nt < 4; nt++)
                part[wave * 64 + nt * 16 + mrow] = p4[nt];
        }
    }
    __syncthreads();
    if (tid < 64) {
        float pred = part[tid] + part[64 + tid] + part[128 + tid] + part[192 + tid] + fc4_b[0];
        preds[p * 256 + e0 + tid] = pred;
    }
}

// ---------------- Kernel 2: propagation, one WAVE per pair (256 blocks) + fused normalize ----------------
__global__ __launch_bounds__(256)
void prop_norm(const int* __restrict__ edges, const float* __restrict__ preds,
               float* __restrict__ rbc_part, int* __restrict__ counter,
               float* __restrict__ out) {
    const int tid = threadIdx.x;
    const int wave = tid >> 6, lane = tid & 63;
    const int p = blockIdx.x * 4 + wave;
    const int s = p >> 5, t = p & 31;
    __shared__ float xw[4][32], xnw[4][32], raccw[4][32];
    __shared__ float red[8][32];
    __shared__ int lastflag;
    int u[4], v[4];
    float pr[4];
#pragma unroll
    for (int j = 0; j < 4; j++) {
        int e = lane + 64 * j;
        u[j] = edges[2 * e];
        v[j] = edges[2 * e + 1];
        pr[j] = preds[p * 256 + e];
    }
    if (lane < 32) { xw[wave][lane] = (lane == s) ? 1.f : 0.f; raccw[wave][lane] = 0.f; }
    const bool active = (s != t);
    for (int step = 0; step < 3; step++) {
        if (lane < 32) xnw[wave][lane] = 0.f;
        __syncthreads();
        if (active) {
#pragma unroll
            for (int j = 0; j < 4; j++)
                atomicAdd(&xnw[wave][v[j]], xw[wave][u[j]] * pr[j]);
        }
        __syncthreads();
        if (lane < 32) { raccw[wave][lane] += xnw[wave][lane]; xw[wave][lane] = xnw[wave][lane]; }
        __syncthreads();
    }
    if (active && lane < 32) atomicAdd(&rbc_part[(p & 63) * 32 + lane], raccw[wave][lane]);
    __syncthreads();  // drains rbc_part atomics before counter bump
    if (tid == 0) lastflag = (atomicAdd(counter, 1) == 255);
    __syncthreads();
    if (!lastflag) return;
    const int node = tid & 31, sub = tid >> 5;
    float vv = 0.f;
#pragma unroll
    for (int g = 0; g < 8; g++)
        vv += atomicAdd(&rbc_part[(sub * 8 + g) * 32 + node], 0.f);  // coherent read
    red[sub][node] = vv;
    __syncthreads();
    if (tid < 32) {
        float acc = 0.f;
#pragma unroll
        for (int sb = 0; sb < 8; sb++) acc += red[sb][tid];
        float tot = acc;
#pragma unroll
        for (int mask = 1; mask < 32; mask <<= 1) tot += __shfl_xor(tot, mask, 32);
        out[tid] = acc / tot;
    }
}

extern "C" void kernel_launch(void* const* d_in, const int* in_sizes, int n_in,
                              void* d_out, int out_size, void* d_ws, size_t ws_size,
                              hipStream_t stream) {
    const float* emb = (const float*)d_in[0];
    const int* edges = (const int*)d_in[1];
    const float* w1 = (const float*)d_in[2];
    const float* b1 = (const float*)d_in[3];
    const float* w2 = (const float*)d_in[4];
    const float* b2 = (const float*)d_in[5];
    const float* w3 = (const float*)d_in[6];
    const float* b3 = (const float*)d_in[7];
    const float* fc1_w = (const float*)d_in[8];
    const float* fc1_b = (const float*)d_in[9];
    const float* fc2_w = (const float*)d_in[10];
    const float* fc2_b = (const float*)d_in[11];
    const float* fc3_w = (const float*)d_in[12];
    const float* fc3_b = (const float*)d_in[13];
    const float* fc4_w = (const float*)d_in[14];
    const float* fc4_b = (const float*)d_in[15];

    float* ws = (float*)d_ws;
    float* F = ws;
    float* preds = ws + PREDS_OFF;
    float* rbc_part = ws + RBCP_OFF;
    int* counter = (int*)(ws + CNT_OFF);
    unsigned short* W1p = (unsigned short*)(ws + W1P_OFF);
    unsigned short* W2p = (unsigned short*)(ws + W2P_OFF);
    unsigned short* W3p = (unsigned short*)(ws + W3P_OFF);
    float* out = (float*)d_out;

    prep_all<<<dim3(369), dim3(256), 0, stream>>>(emb, w1, fc1_w, fc2_w, fc3_w,
                                                  F, W1p, W2p, W3p, rbc_part);
    mlp_kernel<<<dim3(4096), dim3(256), 0, stream>>>(
        F, edges, b1, w2, b2, w3, b3, fc1_b, fc2_b, fc3_b,
        fc4_w, fc4_b, W1p, W2p, W3p, preds);
    prop_norm<<<dim3(256), dim3(256), 0, stream>>>(edges, preds, rbc_part, counter, out);
}

// Round 6
// 166.539 us; speedup vs baseline: 1.0566x; 1.0057x over previous
//
#include <hip/hip_runtime.h>

// ---- ws layout (float offsets) ----
constexpr int F_ELEMS = 4 * 32 * 4 * 48;            // padded-48 conv1 tables
constexpr int PREDS_OFF = F_ELEMS;                  // 24576
constexpr int RBCP_OFF = PREDS_OFF + 1024 * 256;    // rbc_part[64][32]
constexpr int CNT_OFF = RBCP_OFF + 2048;            // completion counter (+pad)
constexpr int W1P_OFF = CNT_OFF + 16;               // fc1 A-frags: 4096 shorts = 2048 f
constexpr int W2P_OFF = W1P_OFF + 2048;             // fc2 A-frags: 32768 shorts = 16384 f
constexpr int W3P_OFF = W2P_OFF + 16384;            // fc3 A-frags: 32768 shorts

typedef __attribute__((ext_vector_type(8))) short short8;
typedef __attribute__((ext_vector_type(4))) short short4v;
typedef __attribute__((ext_vector_type(4))) float f32x4;
typedef __attribute__((ext_vector_type(2))) unsigned int uint2v;

__device__ __forceinline__ unsigned short f2bf(float x) {  // RNE bf16 (prep only)
    unsigned u = __float_as_uint(x);
    u += 0x7FFF + ((u >> 16) & 1);
    return (unsigned short)(u >> 16);
}

// One-instruction packed f32->bf16 pair (low = a, high = b).
__device__ __forceinline__ unsigned cvt_pk_bf16(float a, float b) {
    unsigned r;
    asm("v_cvt_pk_bf16_f32 %0, %1, %2" : "=v"(r) : "v"(a), "v"(b));
    return r;
}

// quad_perm DPP: lane -> lane^m within each 4-lane quad (VALU, no LDS pipe).
template <int CTRL>
__device__ __forceinline__ float qp(float x) {
    return __int_as_float(__builtin_amdgcn_update_dpp(
        0, __float_as_int(x), CTRL, 0xF, 0xF, true));
}

// ---------------- Kernel 0: all preprocessing (single-bf16 weights) ----------------
// b<96: F tables. b<112: W1p (4096). b<240: W2p (32768). b<368: W3p (32768). b==368: zero.
__global__ void prep_all(const float* __restrict__ emb, const float* __restrict__ w1,
                         const float* __restrict__ fc1_w, const float* __restrict__ fc2_w,
                         const float* __restrict__ fc3_w,
                         float* __restrict__ F, unsigned short* __restrict__ W1p,
                         unsigned short* __restrict__ W2p, unsigned short* __restrict__ W3p,
                         float* __restrict__ rbcp_zero) {
    int b = blockIdx.x;
    if (b < 96) {
        int idx = b * 256 + threadIdx.x;  // 24576
        int i = idx % 48;
        int o = (idx / 48) % 4;
        int node = (idx / 192) % 32;
        int c = idx / 6144;
        float acc = 0.f;
        if (i < 46) {
#pragma unroll
            for (int k = 0; k < 3; k++) acc += w1[(o * 4 + c) * 3 + k] * emb[node * 96 + 2 * i + k];
        }
        F[idx] = acc;
        return;
    }
    if (b < 112) {  // fc1 A-layout, K padded 16->32, single bf16
        int t = (b - 96) * 256 + threadIdx.x;  // 4096
        int j = t & 7, lane = (t >> 3) & 63, mt = t >> 9;
        int k = (lane >> 4) * 8 + j, n = mt * 16 + (lane & 15);
        float w = (k < 16) ? fc1_w[k * 128 + n] : 0.f;
        W1p[t] = f2bf(w);
        return;
    }
    if (b < 240) {  // fc2 A-layout [16mt][4ks], single bf16
        int t = (b - 112) * 256 + threadIdx.x;  // 32768
        int j = t & 7, lane = (t >> 3) & 63, ks = (t >> 9) & 3, mt = t >> 11;
        int k = ks * 32 + (lane >> 4) * 8 + j, n = mt * 16 + (lane & 15);
        W2p[t] = f2bf(fc2_w[k * 256 + n]);
        return;
    }
    if (b < 368) {  // fc3 A-layout [8mt][8ks], single bf16
        int t = (b - 240) * 256 + threadIdx.x;  // 32768
        int j = t & 7, lane = (t >> 3) & 63, ks = (t >> 9) & 7, mt = t >> 12;
        int k = ks * 32 + (lane >> 4) * 8 + j, n = mt * 16 + (lane & 15);
        W3p[t] = f2bf(fc3_w[k * 128 + n]);
        return;
    }
    for (int k = threadIdx.x; k < 2064; k += 256) rbcp_zero[k] = 0.f;  // rbc_part + counter
}

// ---------------- Kernel 1: r5 + batched weight prefetch (use the free 64->128 VGPR
// headroom; LDS caps occupancy at 4 blocks/CU so VGPR<=128 costs nothing).
// Established dead ends (do not retry): multi-chunk loop (spills), min-waves=6
// (VGPR clamp+spill), 64-wide sample quarters (flat), fused prop (+19us),
// one-block-per-pair, DPP-for-shfl (r3: neutral), fc2/fc3 64-col quarters for LDS 24K
// (r4: occupancy unchanged, +5.5us -> NOT LDS-limited), cvt_pk epilogues (r5: -3us,
// VALU issue is NOT the critical path; stalls are). ----------------
__global__ __launch_bounds__(256, 4)
void mlp_kernel(const float* __restrict__ F, const int* __restrict__ edges,
                const float* __restrict__ b1v,
                const float* __restrict__ w2, const float* __restrict__ b2,
                const float* __restrict__ w3, const float* __restrict__ b3,
                const float* __restrict__ fc1_b, const float* __restrict__ fc2_b,
                const float* __restrict__ fc3_b,
                const float* __restrict__ fc4_w, const float* __restrict__ fc4_b,
                const unsigned short* __restrict__ W1p, const unsigned short* __restrict__ W2p,
                const unsigned short* __restrict__ W3p,
                float* __restrict__ preds) {
    // LDS (floats): [0,4096) X3-half region, X1 aliases its head; [4096,8192) X2; [8192,8448) part
    __shared__ __align__(16) float smem[8448];
    unsigned short* X1 = (unsigned short*)smem;
    unsigned short* X3h = (unsigned short*)smem;
    unsigned short* X2 = (unsigned short*)(smem + 4096);
    float* part = smem + 8192;

    const int tid = threadIdx.x;
    const int p = blockIdx.x >> 2;
    const int e0 = (blockIdx.x & 3) * 64;
    const int s = p >> 5, t = p & 31;
    if (s == t) return;

    const int lane = tid & 63, wave = tid >> 6;
    const int mrow = lane & 15, quad = lane >> 4;

    const int gsample = tid >> 2, o = tid & 3;  // conv roles
    float h1[23];
    // ---- conv1: table sum (float4 loads, padded-48 rows), pool THEN relu -> regs ----
    {
        const int e = e0 + gsample;
        const int u = edges[2 * e], v = edges[2 * e + 1];
        const f32x4* F0 = (const f32x4*)(F + ((0 * 32 + s) * 4 + o) * 48);
        const f32x4* F1 = (const f32x4*)(F + ((1 * 32 + t) * 4 + o) * 48);
        const f32x4* F2 = (const f32x4*)(F + ((2 * 32 + u) * 4 + o) * 48);
        const f32x4* F3 = (const f32x4*)(F + ((3 * 32 + v) * 4 + o) * 48);
        const float bb = b1v[o];
        float pre[46];
#pragma unroll
        for (int q = 0; q < 12; q++) {
            f32x4 x = F0[q] + F1[q] + F2[q] + F3[q];
#pragma unroll
            for (int z = 0; z < 4; z++) {
                int i = 4 * q + z;
                if (i < 46) pre[i] = x[z] + bb;
            }
        }
#pragma unroll
        for (int j = 0; j < 23; j++) h1[j] = fmaxf(fmaxf(pre[2 * j], pre[2 * j + 1]), 0.f);
    }
    float h2[10];
    // ---- conv2: cross-channel via DPP quad_perm, sliding ring; pool+relu fused ----
    {
        float wm[4][3];  // wm[m][k] = w2[o][o^m][k]
#pragma unroll
        for (int m = 0; m < 4; m++)
#pragma unroll
            for (int k = 0; k < 3; k++) wm[m][k] = w2[o * 12 + (o ^ m) * 3 + k];
        const float bb = b2[o];
        float win[4][3];
#pragma unroll
        for (int j = 0; j < 2; j++) {
            float x = h1[j];
            win[0][j] = x;
            win[1][j] = qp<0xB1>(x);
            win[2][j] = qp<0x4E>(x);
            win[3][j] = qp<0x1B>(x);
        }
        float pre[20];
#pragma unroll
        for (int i = 0; i < 20; i++) {
            float x = h1[i + 2];
            win[0][(i + 2) % 3] = x;
            win[1][(i + 2) % 3] = qp<0xB1>(x);
            win[2][(i + 2) % 3] = qp<0x4E>(x);
            win[3][(i + 2) % 3] = qp<0x1B>(x);
            float acc = bb;
#pragma unroll
            for (int m = 0; m < 4; m++)
#pragma unroll
                for (int k = 0; k < 3; k++)
                    acc = fmaf(wm[m][k], win[m][(i + k) % 3], acc);
            pre[i] = acc;
        }
#pragma unroll
        for (int j = 0; j < 10; j++) h2[j] = fmaxf(fmaxf(pre[2 * j], pre[2 * j + 1]), 0.f);
    }
    // ---- conv3; pool+relu fused; cvt_pk pack -> X1 (bf16 B-frag layout, K 16 pad 32) ----
    {
        float wm[4][3];
#pragma unroll
        for (int m = 0; m < 4; m++)
#pragma unroll
            for (int k = 0; k < 3; k++) wm[m][k] = w3[o * 12 + (o ^ m) * 3 + k];
        const float bb = b3[o];
        float win[4][3];
#pragma unroll
        for (int j = 0; j < 2; j++) {
            float x = h2[j];
            win[0][j] = x;
            win[1][j] = qp<0xB1>(x);
            win[2][j] = qp<0x4E>(x);
            win[3][j] = qp<0x1B>(x);
        }
        float pre[8];
#pragma unroll
        for (int i = 0; i < 8; i++) {
            float x = h2[i + 2];
            win[0][(i + 2) % 3] = x;
            win[1][(i + 2) % 3] = qp<0xB1>(x);
            win[2][(i + 2) % 3] = qp<0x4E>(x);
            win[3][(i + 2) % 3] = qp<0x1B>(x);
            float acc = bb;
#pragma unroll
            for (int m = 0; m < 4; m++)
#pragma unroll
                for (int k = 0; k < 3; k++)
                    acc = fmaf(wm[m][k], win[m][(i + k) % 3], acc);
            pre[i] = acc;
        }
        float v0 = fmaxf(fmaxf(pre[0], pre[1]), 0.f);
        float v1 = fmaxf(fmaxf(pre[2], pre[3]), 0.f);
        float v2 = fmaxf(fmaxf(pre[4], pre[5]), 0.f);
        float v3 = fmaxf(fmaxf(pre[6], pre[7]), 0.f);
        uint2v d;
        d.x = cvt_pk_bf16(v0, v1);
        d.y = cvt_pk_bf16(v2, v3);
        *(uint2v*)(X1 + (((o >> 1) * 64 + gsample) * 8) + (o & 1) * 4) = d;
        uint2v z2 = (uint2v){0u, 0u};  // k in [16,32) zeros
        *(uint2v*)(X1 + ((((o >> 1) + 2) * 64 + gsample) * 8) + (o & 1) * 4) = z2;
    }
    // ---- prefetch fc1 A-frags (8 VGPR) so their latency hides under the barrier ----
    const short8* W1v = (const short8*)W1p;
    short8 w1f[2];
#pragma unroll
    for (int mtl = 0; mtl < 2; mtl++)
        w1f[mtl] = W1v[(wave * 2 + mtl) * 64 + lane];
    __syncthreads();  // barrier 1: X1 visible to all waves
    // ---- fc1 MFMA: A=w1f (prefetched), B=X1 ----
    {
        short8 bnt[4];
#pragma unroll
        for (int nt = 0; nt < 4; nt++)
            bnt[nt] = *(const short8*)(X1 + (quad * 64 + nt * 16 + mrow) * 8);
        f32x4 acc1[2][4];
#pragma unroll
        for (int a = 0; a < 2; a++)
#pragma unroll
            for (int b = 0; b < 4; b++) acc1[a][b] = (f32x4){0.f, 0.f, 0.f, 0.f};
#pragma unroll
        for (int mtl = 0; mtl < 2; mtl++) {
#pragma unroll
            for (int nt = 0; nt < 4; nt++)
                acc1[mtl][nt] = __builtin_amdgcn_mfma_f32_16x16x32_bf16(w1f[mtl], bnt[nt], acc1[mtl][nt], 0, 0, 0);
        }
        // epilogue straight to X2 (disjoint region; no barrier needed)
#pragma unroll
        for (int mtl = 0; mtl < 2; mtl++) {
            const int mt = wave * 2 + mtl;
            const int n0 = mt * 16 + quad * 4;
            f32x4 b4 = *(const f32x4*)(fc1_b + n0);
#pragma unroll
            for (int nt = 0; nt < 4; nt++) {
                float x0 = fmaxf(acc1[mtl][nt][0] + b4[0], 0.f);
                float x1 = fmaxf(acc1[mtl][nt][1] + b4[1], 0.f);
                float x2 = fmaxf(acc1[mtl][nt][2] + b4[2], 0.f);
                float x3 = fmaxf(acc1[mtl][nt][3] + b4[3], 0.f);
                uint2v d;
                d.x = cvt_pk_bf16(x0, x1);
                d.y = cvt_pk_bf16(x2, x3);
                *(uint2v*)(X2 + ((n0 >> 3) * 64 + nt * 16 + mrow) * 8 + (n0 & 7)) = d;
            }
        }
    }
    __syncthreads();  // barrier 2: X2 visible; X1 reads done (X3h writes may follow)
    // ---- fc2 -> fc3 in two K=128 halves through X3h, with batched weight prefetch ----
    const short8* W2v = (const short8*)W2p;
    const short8* W3v = (const short8*)W3p;
    f32x4 acc3[2][4];
#pragma unroll
    for (int a = 0; a < 2; a++)
#pragma unroll
        for (int b = 0; b < 4; b++) acc3[a][b] = (f32x4){0.f, 0.f, 0.f, 0.f};
#pragma unroll
    for (int h = 0; h < 2; h++) {
        // batch-issue ALL 8 fc2 A-frags for this half (32 VGPR, 8 loads in flight)
        short8 w2f[2][4];
#pragma unroll
        for (int mtl = 0; mtl < 2; mtl++)
#pragma unroll
            for (int ks = 0; ks < 4; ks++)
                w2f[mtl][ks] = W2v[((h * 8 + wave * 2 + mtl) * 4 + ks) * 64 + lane];
        f32x4 acc2[2][4];
#pragma unroll
        for (int a = 0; a < 2; a++)
#pragma unroll
            for (int b = 0; b < 4; b++) acc2[a][b] = (f32x4){0.f, 0.f, 0.f, 0.f};
#pragma unroll
        for (int ks = 0; ks < 4; ks++) {
            short8 bfr[4];
#pragma unroll
            for (int nt = 0; nt < 4; nt++)
                bfr[nt] = *(const short8*)(X2 + ((ks * 4 + quad) * 64 + nt * 16 + mrow) * 8);
#pragma unroll
            for (int mtl = 0; mtl < 2; mtl++) {
#pragma unroll
                for (int nt = 0; nt < 4; nt++)
                    acc2[mtl][nt] = __builtin_amdgcn_mfma_f32_16x16x32_bf16(w2f[mtl][ks], bfr[nt], acc2[mtl][nt], 0, 0, 0);
            }
        }
        // batch-issue ALL 8 fc3 A-frags for this half now; latency hides under
        // the fc2 epilogue + barrier drain (w2f dead, acc2 dying -> fits 128 VGPR)
        short8 w3f[2][4];
#pragma unroll
        for (int mtl = 0; mtl < 2; mtl++)
#pragma unroll
            for (int ksl = 0; ksl < 4; ksl++)
                w3f[mtl][ksl] = W3v[((wave * 2 + mtl) * 8 + h * 4 + ksl) * 64 + lane];
        // epilogue -> X3h (k-local = n - h*128)
#pragma unroll
        for (int mtl = 0; mtl < 2; mtl++) {
            const int mt = h * 8 + wave * 2 + mtl;
            const int n0 = mt * 16 + quad * 4;
            const int kl = n0 - h * 128;
            f32x4 b4 = *(const f32x4*)(fc2_b + n0);
#pragma unroll
            for (int nt = 0; nt < 4; nt++) {
                float x0 = fmaxf(acc2[mtl][nt][0] + b4[0], 0.f);
                float x1 = fmaxf(acc2[mtl][nt][1] + b4[1], 0.f);
                float x2 = fmaxf(acc2[mtl][nt][2] + b4[2], 0.f);
                float x3 = fmaxf(acc2[mtl][nt][3] + b4[3], 0.f);
                uint2v d;
                d.x = cvt_pk_bf16(x0, x1);
                d.y = cvt_pk_bf16(x2, x3);
                *(uint2v*)(X3h + ((kl >> 3) * 64 + nt * 16 + mrow) * 8 + (kl & 7)) = d;
            }
        }
        __syncthreads();  // barrier 3/5: X3h half ready
        // fc3 accumulate this half's 4 ks (weights already in registers)
#pragma unroll
        for (int ksl = 0; ksl < 4; ksl++) {
            short8 bfr[4];
#pragma unroll
            for (int nt = 0; nt < 4; nt++)
                bfr[nt] = *(const short8*)(X3h + ((ksl * 4 + quad) * 64 + nt * 16 + mrow) * 8);
#pragma unroll
            for (int mtl = 0; mtl < 2; mtl++) {
#pragma unroll
                for (int nt = 0; nt < 4; nt++)
                    acc3[mtl][nt] = __builtin_amdgcn_mfma_f32_16x16x32_bf16(w3f[mtl][ksl], bfr[nt], acc3[mtl][nt], 0, 0, 0);
            }
        }
        __syncthreads();  // barrier 4/6: X3h reads done before reuse / part writes
    }
    // ---- fused fc4 ----
    {
        float p4[4] = {0.f, 0.f, 0.f, 0.f};
#pragma unroll
        for (int mtl = 0; mtl < 2; mtl++) {
            const int mt = wave * 2 + mtl;
            const int n0 = mt * 16 + quad * 4;
            f32x4 b4 = *(const f32x4*)(fc3_b + n0);
            f32x4 w44 = *(const f32x4*)(fc4_w + n0);
#pragma unroll
            for (int nt = 0; nt < 4; nt++)
#pragma unroll
                for (int r = 0; r < 4; r++)
                    p4[nt] = fmaf(fmaxf(acc3[mtl][nt][r] + b4[r], 0.f), w44[r], p4[nt]);
        }
#pragma unroll
        for (int nt = 0; nt < 4; nt++) {
            p4[nt] += __shfl_xor(p4[nt], 16, 64);
            p4[nt] += __shfl_xor(p4[nt], 32, 64);
        }
        if (quad == 0) {
#pragma unroll
            for (int nt = 0; nt < 4; nt++)
                part[wave * 64 + nt * 16 + mrow] = p4[nt];
        }
    }
    __syncthreads();
    if (tid < 64) {
        float pred = part[tid] + part[64 + tid] + part[128 + tid] + part[192 + tid] + fc4_b[0];
        preds[p * 256 + e0 + tid] = pred;
    }
}

// ---------------- Kernel 2: propagation, one WAVE per pair (256 blocks) + fused normalize ----------------
__global__ __launch_bounds__(256)
void prop_norm(const int* __restrict__ edges, const float* __restrict__ preds,
               float* __restrict__ rbc_part, int* __restrict__ counter,
               float* __restrict__ out) {
    const int tid = threadIdx.x;
    const int wave = tid >> 6, lane = tid & 63;
    const int p = blockIdx.x * 4 + wave;
    const int s = p >> 5, t = p & 31;
    __shared__ float xw[4][32], xnw[4][32], raccw[4][32];
    __shared__ float red[8][32];
    __shared__ int lastflag;
    int u[4], v[4];
    float pr[4];
#pragma unroll
    for (int j = 0; j < 4; j++) {
        int e = lane + 64 * j;
        u[j] = edges[2 * e];
        v[j] = edges[2 * e + 1];
        pr[j] = preds[p * 256 + e];
    }
    if (lane < 32) { xw[wave][lane] = (lane == s) ? 1.f : 0.f; raccw[wave][lane] = 0.f; }
    const bool active = (s != t);
    for (int step = 0; step < 3; step++) {
        if (lane < 32) xnw[wave][lane] = 0.f;
        __syncthreads();
        if (active) {
#pragma unroll
            for (int j = 0; j < 4; j++)
                atomicAdd(&xnw[wave][v[j]], xw[wave][u[j]] * pr[j]);
        }
        __syncthreads();
        if (lane < 32) { raccw[wave][lane] += xnw[wave][lane]; xw[wave][lane] = xnw[wave][lane]; }
        __syncthreads();
    }
    if (active && lane < 32) atomicAdd(&rbc_part[(p & 63) * 32 + lane], raccw[wave][lane]);
    __syncthreads();  // drains rbc_part atomics before counter bump
    if (tid == 0) lastflag = (atomicAdd(counter, 1) == 255);
    __syncthreads();
    if (!lastflag) return;
    const int node = tid & 31, sub = tid >> 5;
    float vv = 0.f;
#pragma unroll
    for (int g = 0; g < 8; g++)
        vv += atomicAdd(&rbc_part[(sub * 8 + g) * 32 + node], 0.f);  // coherent read
    red[sub][node] = vv;
    __syncthreads();
    if (tid < 32) {
        float acc = 0.f;
#pragma unroll
        for (int sb = 0; sb < 8; sb++) acc += red[sb][tid];
        float tot = acc;
#pragma unroll
        for (int mask = 1; mask < 32; mask <<= 1) tot += __shfl_xor(tot, mask, 32);
        out[tid] = acc / tot;
    }
}

extern "C" void kernel_launch(void* const* d_in, const int* in_sizes, int n_in,
                              void* d_out, int out_size, void* d_ws, size_t ws_size,
                              hipStream_t stream) {
    const float* emb = (const float*)d_in[0];
    const int* edges = (const int*)d_in[1];
    const float* w1 = (const float*)d_in[2];
    const float* b1 = (const float*)d_in[3];
    const float* w2 = (const float*)d_in[4];
    const float* b2 = (const float*)d_in[5];
    const float* w3 = (const float*)d_in[6];
    const float* b3 = (const float*)d_in[7];
    const float* fc1_w = (const float*)d_in[8];
    const float* fc1_b = (const float*)d_in[9];
    const float* fc2_w = (const float*)d_in[10];
    const float* fc2_b = (const float*)d_in[11];
    const float* fc3_w = (const float*)d_in[12];
    const float* fc3_b = (const float*)d_in[13];
    const float* fc4_w = (const float*)d_in[14];
    const float* fc4_b = (const float*)d_in[15];

    float* ws = (float*)d_ws;
    float* F = ws;
    float* preds = ws + PREDS_OFF;
    float* rbc_part = ws + RBCP_OFF;
    int* counter = (int*)(ws + CNT_OFF);
    unsigned short* W1p = (unsigned short*)(ws + W1P_OFF);
    unsigned short* W2p = (unsigned short*)(ws + W2P_OFF);
    unsigned short* W3p = (unsigned short*)(ws + W3P_OFF);
    float* out = (float*)d_out;

    prep_all<<<dim3(369), dim3(256), 0, stream>>>(emb, w1, fc1_w, fc2_w, fc3_w,
                                                  F, W1p, W2p, W3p, rbc_part);
    mlp_kernel<<<dim3(4096), dim3(256), 0, stream>>>(
        F, edges, b1, w2, b2, w3, b3, fc1_b, fc2_b, fc3_b,
        fc4_w, fc4_b, W1p, W2p, W3p, preds);
    prop_norm<<<dim3(256), dim3(256), 0, stream>>>(edges, preds, rbc_part, counter, out);
}

// Round 7
// 165.542 us; speedup vs baseline: 1.0630x; 1.0060x over previous
//
#include <hip/hip_runtime.h>

// ---- ws layout (float offsets) ----
constexpr int F_ELEMS = 4 * 32 * 4 * 48;            // padded-48 conv1 tables
constexpr int PREDS_OFF = F_ELEMS;                  // 24576
constexpr int RBCP_OFF = PREDS_OFF + 1024 * 256;    // rbc_part[64][32]
constexpr int CNT_OFF = RBCP_OFF + 2048;            // (legacy counter slot, unused)
constexpr int W1P_OFF = CNT_OFF + 16;               // fc1 A-frags: 4096 shorts = 2048 f
constexpr int W2P_OFF = W1P_OFF + 2048;             // fc2 A-frags: 32768 shorts = 16384 f
constexpr int W3P_OFF = W2P_OFF + 16384;            // fc3 A-frags: 32768 shorts

typedef __attribute__((ext_vector_type(8))) short short8;
typedef __attribute__((ext_vector_type(4))) short short4v;
typedef __attribute__((ext_vector_type(4))) float f32x4;
typedef __attribute__((ext_vector_type(2))) unsigned int uint2v;

__device__ __forceinline__ unsigned short f2bf(float x) {  // RNE bf16 (prep only)
    unsigned u = __float_as_uint(x);
    u += 0x7FFF + ((u >> 16) & 1);
    return (unsigned short)(u >> 16);
}

// One-instruction packed f32->bf16 pair (low = a, high = b).
__device__ __forceinline__ unsigned cvt_pk_bf16(float a, float b) {
    unsigned r;
    asm("v_cvt_pk_bf16_f32 %0, %1, %2" : "=v"(r) : "v"(a), "v"(b));
    return r;
}

// quad_perm DPP: lane -> lane^m within each 4-lane quad (VALU, no LDS pipe).
template <int CTRL>
__device__ __forceinline__ float qp(float x) {
    return __int_as_float(__builtin_amdgcn_update_dpp(
        0, __float_as_int(x), CTRL, 0xF, 0xF, true));
}

// ---------------- Kernel 0: all preprocessing (single-bf16 weights) ----------------
// b<96: F tables. b<112: W1p (4096). b<240: W2p (32768). b<368: W3p (32768). b==368: zero.
__global__ void prep_all(const float* __restrict__ emb, const float* __restrict__ w1,
                         const float* __restrict__ fc1_w, const float* __restrict__ fc2_w,
                         const float* __restrict__ fc3_w,
                         float* __restrict__ F, unsigned short* __restrict__ W1p,
                         unsigned short* __restrict__ W2p, unsigned short* __restrict__ W3p,
                         float* __restrict__ rbcp_zero) {
    int b = blockIdx.x;
    if (b < 96) {
        int idx = b * 256 + threadIdx.x;  // 24576
        int i = idx % 48;
        int o = (idx / 48) % 4;
        int node = (idx / 192) % 32;
        int c = idx / 6144;
        float acc = 0.f;
        if (i < 46) {
#pragma unroll
            for (int k = 0; k < 3; k++) acc += w1[(o * 4 + c) * 3 + k] * emb[node * 96 + 2 * i + k];
        }
        F[idx] = acc;
        return;
    }
    if (b < 112) {  // fc1 A-layout, K padded 16->32, single bf16
        int t = (b - 96) * 256 + threadIdx.x;  // 4096
        int j = t & 7, lane = (t >> 3) & 63, mt = t >> 9;
        int k = (lane >> 4) * 8 + j, n = mt * 16 + (lane & 15);
        float w = (k < 16) ? fc1_w[k * 128 + n] : 0.f;
        W1p[t] = f2bf(w);
        return;
    }
    if (b < 240) {  // fc2 A-layout [16mt][4ks], single bf16
        int t = (b - 112) * 256 + threadIdx.x;  // 32768
        int j = t & 7, lane = (t >> 3) & 63, ks = (t >> 9) & 3, mt = t >> 11;
        int k = ks * 32 + (lane >> 4) * 8 + j, n = mt * 16 + (lane & 15);
        W2p[t] = f2bf(fc2_w[k * 256 + n]);
        return;
    }
    if (b < 368) {  // fc3 A-layout [8mt][8ks], single bf16
        int t = (b - 240) * 256 + threadIdx.x;  // 32768
        int j = t & 7, lane = (t >> 3) & 63, ks = (t >> 9) & 7, mt = t >> 12;
        int k = ks * 32 + (lane >> 4) * 8 + j, n = mt * 16 + (lane & 15);
        W3p[t] = f2bf(fc3_w[k * 128 + n]);
        return;
    }
    for (int k = threadIdx.x; k < 2064; k += 256) rbcp_zero[k] = 0.f;  // rbc_part (+legacy)
}

// ---------------- Kernel 1: unchanged from r6 (85.9us, passing). ----------------
// Established dead ends (do not retry): multi-chunk loop (spills), min-waves=6
// (VGPR clamp+spill), 64-wide sample quarters (flat), fused prop (+19us),
// one-block-per-pair, DPP-for-shfl (r3: neutral), fc2/fc3 64-col quarters for LDS 24K
// (r4: occupancy unchanged, +5.5us -> NOT LDS-limited), cvt_pk epilogues (r5: -3us,
// VALU issue is NOT the critical path), batched weight prefetch (r6: compiler re-sank,
// VGPR stayed 64, neutral).
__global__ __launch_bounds__(256, 4)
void mlp_kernel(const float* __restrict__ F, const int* __restrict__ edges,
                const float* __restrict__ b1v,
                const float* __restrict__ w2, const float* __restrict__ b2,
                const float* __restrict__ w3, const float* __restrict__ b3,
                const float* __restrict__ fc1_b, const float* __restrict__ fc2_b,
                const float* __restrict__ fc3_b,
                const float* __restrict__ fc4_w, const float* __restrict__ fc4_b,
                const unsigned short* __restrict__ W1p, const unsigned short* __restrict__ W2p,
                const unsigned short* __restrict__ W3p,
                float* __restrict__ preds) {
    // LDS (floats): [0,4096) X3-half region, X1 aliases its head; [4096,8192) X2; [8192,8448) part
    __shared__ __align__(16) float smem[8448];
    unsigned short* X1 = (unsigned short*)smem;
    unsigned short* X3h = (unsigned short*)smem;
    unsigned short* X2 = (unsigned short*)(smem + 4096);
    float* part = smem + 8192;

    const int tid = threadIdx.x;
    const int p = blockIdx.x >> 2;
    const int e0 = (blockIdx.x & 3) * 64;
    const int s = p >> 5, t = p & 31;
    if (s == t) return;

    const int lane = tid & 63, wave = tid >> 6;
    const int mrow = lane & 15, quad = lane >> 4;

    const int gsample = tid >> 2, o = tid & 3;  // conv roles
    float h1[23];
    // ---- conv1: table sum (float4 loads, padded-48 rows), pool THEN relu -> regs ----
    {
        const int e = e0 + gsample;
        const int u = edges[2 * e], v = edges[2 * e + 1];
        const f32x4* F0 = (const f32x4*)(F + ((0 * 32 + s) * 4 + o) * 48);
        const f32x4* F1 = (const f32x4*)(F + ((1 * 32 + t) * 4 + o) * 48);
        const f32x4* F2 = (const f32x4*)(F + ((2 * 32 + u) * 4 + o) * 48);
        const f32x4* F3 = (const f32x4*)(F + ((3 * 32 + v) * 4 + o) * 48);
        const float bb = b1v[o];
        float pre[46];
#pragma unroll
        for (int q = 0; q < 12; q++) {
            f32x4 x = F0[q] + F1[q] + F2[q] + F3[q];
#pragma unroll
            for (int z = 0; z < 4; z++) {
                int i = 4 * q + z;
                if (i < 46) pre[i] = x[z] + bb;
            }
        }
#pragma unroll
        for (int j = 0; j < 23; j++) h1[j] = fmaxf(fmaxf(pre[2 * j], pre[2 * j + 1]), 0.f);
    }
    float h2[10];
    // ---- conv2: cross-channel via DPP quad_perm, sliding ring; pool+relu fused ----
    {
        float wm[4][3];  // wm[m][k] = w2[o][o^m][k]
#pragma unroll
        for (int m = 0; m < 4; m++)
#pragma unroll
            for (int k = 0; k < 3; k++) wm[m][k] = w2[o * 12 + (o ^ m) * 3 + k];
        const float bb = b2[o];
        float win[4][3];
#pragma unroll
        for (int j = 0; j < 2; j++) {
            float x = h1[j];
            win[0][j] = x;
            win[1][j] = qp<0xB1>(x);
            win[2][j] = qp<0x4E>(x);
            win[3][j] = qp<0x1B>(x);
        }
        float pre[20];
#pragma unroll
        for (int i = 0; i < 20; i++) {
            float x = h1[i + 2];
            win[0][(i + 2) % 3] = x;
            win[1][(i + 2) % 3] = qp<0xB1>(x);
            win[2][(i + 2) % 3] = qp<0x4E>(x);
            win[3][(i + 2) % 3] = qp<0x1B>(x);
            float acc = bb;
#pragma unroll
            for (int m = 0; m < 4; m++)
#pragma unroll
                for (int k = 0; k < 3; k++)
                    acc = fmaf(wm[m][k], win[m][(i + k) % 3], acc);
            pre[i] = acc;
        }
#pragma unroll
        for (int j = 0; j < 10; j++) h2[j] = fmaxf(fmaxf(pre[2 * j], pre[2 * j + 1]), 0.f);
    }
    // ---- conv3; pool+relu fused; cvt_pk pack -> X1 (bf16 B-frag layout, K 16 pad 32) ----
    {
        float wm[4][3];
#pragma unroll
        for (int m = 0; m < 4; m++)
#pragma unroll
            for (int k = 0; k < 3; k++) wm[m][k] = w3[o * 12 + (o ^ m) * 3 + k];
        const float bb = b3[o];
        float win[4][3];
#pragma unroll
        for (int j = 0; j < 2; j++) {
            float x = h2[j];
            win[0][j] = x;
            win[1][j] = qp<0xB1>(x);
            win[2][j] = qp<0x4E>(x);
            win[3][j] = qp<0x1B>(x);
        }
        float pre[8];
#pragma unroll
        for (int i = 0; i < 8; i++) {
            float x = h2[i + 2];
            win[0][(i + 2) % 3] = x;
            win[1][(i + 2) % 3] = qp<0xB1>(x);
            win[2][(i + 2) % 3] = qp<0x4E>(x);
            win[3][(i + 2) % 3] = qp<0x1B>(x);
            float acc = bb;
#pragma unroll
            for (int m = 0; m < 4; m++)
#pragma unroll
                for (int k = 0; k < 3; k++)
                    acc = fmaf(wm[m][k], win[m][(i + k) % 3], acc);
            pre[i] = acc;
        }
        float v0 = fmaxf(fmaxf(pre[0], pre[1]), 0.f);
        float v1 = fmaxf(fmaxf(pre[2], pre[3]), 0.f);
        float v2 = fmaxf(fmaxf(pre[4], pre[5]), 0.f);
        float v3 = fmaxf(fmaxf(pre[6], pre[7]), 0.f);
        uint2v d;
        d.x = cvt_pk_bf16(v0, v1);
        d.y = cvt_pk_bf16(v2, v3);
        *(uint2v*)(X1 + (((o >> 1) * 64 + gsample) * 8) + (o & 1) * 4) = d;
        uint2v z2 = (uint2v){0u, 0u};  // k in [16,32) zeros
        *(uint2v*)(X1 + ((((o >> 1) + 2) * 64 + gsample) * 8) + (o & 1) * 4) = z2;
    }
    // ---- prefetch fc1 A-frags (8 VGPR) so their latency hides under the barrier ----
    const short8* W1v = (const short8*)W1p;
    short8 w1f[2];
#pragma unroll
    for (int mtl = 0; mtl < 2; mtl++)
        w1f[mtl] = W1v[(wave * 2 + mtl) * 64 + lane];
    __syncthreads();  // barrier 1: X1 visible to all waves
    // ---- fc1 MFMA: A=w1f (prefetched), B=X1 ----
    {
        short8 bnt[4];
#pragma unroll
        for (int nt = 0; nt < 4; nt++)
            bnt[nt] = *(const short8*)(X1 + (quad * 64 + nt * 16 + mrow) * 8);
        f32x4 acc1[2][4];
#pragma unroll
        for (int a = 0; a < 2; a++)
#pragma unroll
            for (int b = 0; b < 4; b++) acc1[a][b] = (f32x4){0.f, 0.f, 0.f, 0.f};
#pragma unroll
        for (int mtl = 0; mtl < 2; mtl++) {
#pragma unroll
            for (int nt = 0; nt < 4; nt++)
                acc1[mtl][nt] = __builtin_amdgcn_mfma_f32_16x16x32_bf16(w1f[mtl], bnt[nt], acc1[mtl][nt], 0, 0, 0);
        }
        // epilogue straight to X2 (disjoint region; no barrier needed)
#pragma unroll
        for (int mtl = 0; mtl < 2; mtl++) {
            const int mt = wave * 2 + mtl;
            const int n0 = mt * 16 + quad * 4;
            f32x4 b4 = *(const f32x4*)(fc1_b + n0);
#pragma unroll
            for (int nt = 0; nt < 4; nt++) {
                float x0 = fmaxf(acc1[mtl][nt][0] + b4[0], 0.f);
                float x1 = fmaxf(acc1[mtl][nt][1] + b4[1], 0.f);
                float x2 = fmaxf(acc1[mtl][nt][2] + b4[2], 0.f);
                float x3 = fmaxf(acc1[mtl][nt][3] + b4[3], 0.f);
                uint2v d;
                d.x = cvt_pk_bf16(x0, x1);
                d.y = cvt_pk_bf16(x2, x3);
                *(uint2v*)(X2 + ((n0 >> 3) * 64 + nt * 16 + mrow) * 8 + (n0 & 7)) = d;
            }
        }
    }
    __syncthreads();  // barrier 2: X2 visible; X1 reads done (X3h writes may follow)
    // ---- fc2 -> fc3 in two K=128 halves through X3h, with batched weight prefetch ----
    const short8* W2v = (const short8*)W2p;
    const short8* W3v = (const short8*)W3p;
    f32x4 acc3[2][4];
#pragma unroll
    for (int a = 0; a < 2; a++)
#pragma unroll
        for (int b = 0; b < 4; b++) acc3[a][b] = (f32x4){0.f, 0.f, 0.f, 0.f};
#pragma unroll
    for (int h = 0; h < 2; h++) {
        // batch-issue ALL 8 fc2 A-frags for this half (32 VGPR, 8 loads in flight)
        short8 w2f[2][4];
#pragma unroll
        for (int mtl = 0; mtl < 2; mtl++)
#pragma unroll
            for (int ks = 0; ks < 4; ks++)
                w2f[mtl][ks] = W2v[((h * 8 + wave * 2 + mtl) * 4 + ks) * 64 + lane];
        f32x4 acc2[2][4];
#pragma unroll
        for (int a = 0; a < 2; a++)
#pragma unroll
            for (int b = 0; b < 4; b++) acc2[a][b] = (f32x4){0.f, 0.f, 0.f, 0.f};
#pragma unroll
        for (int ks = 0; ks < 4; ks++) {
            short8 bfr[4];
#pragma unroll
            for (int nt = 0; nt < 4; nt++)
                bfr[nt] = *(const short8*)(X2 + ((ks * 4 + quad) * 64 + nt * 16 + mrow) * 8);
#pragma unroll
            for (int mtl = 0; mtl < 2; mtl++) {
#pragma unroll
                for (int nt = 0; nt < 4; nt++)
                    acc2[mtl][nt] = __builtin_amdgcn_mfma_f32_16x16x32_bf16(w2f[mtl][ks], bfr[nt], acc2[mtl][nt], 0, 0, 0);
            }
        }
        // batch-issue ALL 8 fc3 A-frags for this half now; latency hides under
        // the fc2 epilogue + barrier drain
        short8 w3f[2][4];
#pragma unroll
        for (int mtl = 0; mtl < 2; mtl++)
#pragma unroll
            for (int ksl = 0; ksl < 4; ksl++)
                w3f[mtl][ksl] = W3v[((wave * 2 + mtl) * 8 + h * 4 + ksl) * 64 + lane];
        // epilogue -> X3h (k-local = n - h*128)
#pragma unroll
        for (int mtl = 0; mtl < 2; mtl++) {
            const int mt = h * 8 + wave * 2 + mtl;
            const int n0 = mt * 16 + quad * 4;
            const int kl = n0 - h * 128;
            f32x4 b4 = *(const f32x4*)(fc2_b + n0);
#pragma unroll
            for (int nt = 0; nt < 4; nt++) {
                float x0 = fmaxf(acc2[mtl][nt][0] + b4[0], 0.f);
                float x1 = fmaxf(acc2[mtl][nt][1] + b4[1], 0.f);
                float x2 = fmaxf(acc2[mtl][nt][2] + b4[2], 0.f);
                float x3 = fmaxf(acc2[mtl][nt][3] + b4[3], 0.f);
                uint2v d;
                d.x = cvt_pk_bf16(x0, x1);
                d.y = cvt_pk_bf16(x2, x3);
                *(uint2v*)(X3h + ((kl >> 3) * 64 + nt * 16 + mrow) * 8 + (kl & 7)) = d;
            }
        }
        __syncthreads();  // barrier 3/5: X3h half ready
        // fc3 accumulate this half's 4 ks (weights already in registers)
#pragma unroll
        for (int ksl = 0; ksl < 4; ksl++) {
            short8 bfr[4];
#pragma unroll
            for (int nt = 0; nt < 4; nt++)
                bfr[nt] = *(const short8*)(X3h + ((ksl * 4 + quad) * 64 + nt * 16 + mrow) * 8);
#pragma unroll
            for (int mtl = 0; mtl < 2; mtl++) {
#pragma unroll
                for (int nt = 0; nt < 4; nt++)
                    acc3[mtl][nt] = __builtin_amdgcn_mfma_f32_16x16x32_bf16(w3f[mtl][ksl], bfr[nt], acc3[mtl][nt], 0, 0, 0);
            }
        }
        __syncthreads();  // barrier 4/6: X3h reads done before reuse / part writes
    }
    // ---- fused fc4 ----
    {
        float p4[4] = {0.f, 0.f, 0.f, 0.f};
#pragma unroll
        for (int mtl = 0; mtl < 2; mtl++) {
            const int mt = wave * 2 + mtl;
            const int n0 = mt * 16 + quad * 4;
            f32x4 b4 = *(const f32x4*)(fc3_b + n0);
            f32x4 w44 = *(const f32x4*)(fc4_w + n0);
#pragma unroll
            for (int nt = 0; nt < 4; nt++)
#pragma unroll
                for (int r = 0; r < 4; r++)
                    p4[nt] = fmaf(fmaxf(acc3[mtl][nt][r] + b4[r], 0.f), w44[r], p4[nt]);
        }
#pragma unroll
        for (int nt = 0; nt < 4; nt++) {
            p4[nt] += __shfl_xor(p4[nt], 16, 64);
            p4[nt] += __shfl_xor(p4[nt], 32, 64);
        }
        if (quad == 0) {
#pragma unroll
            for (int nt = 0; nt < 4; nt++)
                part[wave * 64 + nt * 16 + mrow] = p4[nt];
        }
    }
    __syncthreads();
    if (tid < 64) {
        float pred = part[tid] + part[64 + tid] + part[128 + tid] + part[192 + tid] + fc4_b[0];
        preds[p * 256 + e0 + tid] = pred;
    }
}

// ---------------- Kernel 2: propagation only, one WAVE per pair (256 blocks).
// r7 change: counter/flag protocol + 2048 atomicAdd(p,0) coherent-read RMWs removed;
// normalize moved to a tiny 4th kernel (kernel boundary = free grid barrier + coherence).
__global__ __launch_bounds__(256)
void prop_kernel(const int* __restrict__ edges, const float* __restrict__ preds,
                 float* __restrict__ rbc_part) {
    const int tid = threadIdx.x;
    const int wave = tid >> 6, lane = tid & 63;
    const int p = blockIdx.x * 4 + wave;
    const int s = p >> 5, t = p & 31;
    __shared__ float xw[4][32], xnw[4][32], raccw[4][32];
    int u[4], v[4];
    float pr[4];
#pragma unroll
    for (int j = 0; j < 4; j++) {
        int e = lane + 64 * j;
        u[j] = edges[2 * e];
        v[j] = edges[2 * e + 1];
        pr[j] = preds[p * 256 + e];
    }
    if (lane < 32) { xw[wave][lane] = (lane == s) ? 1.f : 0.f; raccw[wave][lane] = 0.f; }
    const bool active = (s != t);
    for (int step = 0; step < 3; step++) {
        if (lane < 32) xnw[wave][lane] = 0.f;
        __syncthreads();
        if (active) {
#pragma unroll
            for (int j = 0; j < 4; j++)
                atomicAdd(&xnw[wave][v[j]], xw[wave][u[j]] * pr[j]);
        }
        __syncthreads();
        if (lane < 32) { raccw[wave][lane] += xnw[wave][lane]; xw[wave][lane] = xnw[wave][lane]; }
        __syncthreads();
    }
    if (active && lane < 32) atomicAdd(&rbc_part[(p & 63) * 32 + lane], raccw[wave][lane]);
}

// ---------------- Kernel 3: final reduce + normalize (1 block). Plain loads —
// kernel boundary guarantees visibility of prop_kernel's device-scope atomics.
__global__ __launch_bounds__(256)
void norm_kernel(const float* __restrict__ rbc_part, float* __restrict__ out) {
    const int tid = threadIdx.x;
    const int node = tid & 31, sub = tid >> 5;
    __shared__ float red[8][32];
    float vv = 0.f;
#pragma unroll
    for (int g = 0; g < 8; g++)
        vv += rbc_part[(sub * 8 + g) * 32 + node];
    red[sub][node] = vv;
    __syncthreads();
    if (tid < 32) {
        float acc = 0.f;
#pragma unroll
        for (int sb = 0; sb < 8; sb++) acc += red[sb][tid];
        float tot = acc;
#pragma unroll
        for (int mask = 1; mask < 32; mask <<= 1) tot += __shfl_xor(tot, mask, 32);
        out[tid] = acc / tot;
    }
}

extern "C" void kernel_launch(void* const* d_in, const int* in_sizes, int n_in,
                              void* d_out, int out_size, void* d_ws, size_t ws_size,
                              hipStream_t stream) {
    const float* emb = (const float*)d_in[0];
    const int* edges = (const int*)d_in[1];
    const float* w1 = (const float*)d_in[2];
    const float* b1 = (const float*)d_in[3];
    const float* w2 = (const float*)d_in[4];
    const float* b2 = (const float*)d_in[5];
    const float* w3 = (const float*)d_in[6];
    const float* b3 = (const float*)d_in[7];
    const float* fc1_w = (const float*)d_in[8];
    const float* fc1_b = (const float*)d_in[9];
    const float* fc2_w = (const float*)d_in[10];
    const float* fc2_b = (const float*)d_in[11];
    const float* fc3_w = (const float*)d_in[12];
    const float* fc3_b = (const float*)d_in[13];
    const float* fc4_w = (const float*)d_in[14];
    const float* fc4_b = (const float*)d_in[15];

    float* ws = (float*)d_ws;
    float* F = ws;
    float* preds = ws + PREDS_OFF;
    float* rbc_part = ws + RBCP_OFF;
    unsigned short* W1p = (unsigned short*)(ws + W1P_OFF);
    unsigned short* W2p = (unsigned short*)(ws + W2P_OFF);
    unsigned short* W3p = (unsigned short*)(ws + W3P_OFF);
    float* out = (float*)d_out;

    prep_all<<<dim3(369), dim3(256), 0, stream>>>(emb, w1, fc1_w, fc2_w, fc3_w,
                                                  F, W1p, W2p, W3p, rbc_part);
    mlp_kernel<<<dim3(4096), dim3(256), 0, stream>>>(
        F, edges, b1, w2, b2, w3, b3, fc1_b, fc2_b, fc3_b,
        fc4_w, fc4_b, W1p, W2p, W3p, preds);
    prop_kernel<<<dim3(256), dim3(256), 0, stream>>>(edges, preds, rbc_part);
    norm_kernel<<<dim3(1), dim3(256), 0, stream>>>(rbc_part, out);
}

// Round 8
// 163.238 us; speedup vs baseline: 1.0780x; 1.0141x over previous
//
#include <hip/hip_runtime.h>

// ---- ws layout (float offsets) ----
constexpr int F_ELEMS = 4 * 32 * 4 * 48;            // padded-48 conv1 tables
constexpr int PREDS_OFF = F_ELEMS;                  // 24576
constexpr int RBCP_OFF = PREDS_OFF + 1024 * 256;    // rbc_part[64][32]
constexpr int CNT_OFF = RBCP_OFF + 2048;            // (legacy counter slot, unused)
constexpr int W1P_OFF = CNT_OFF + 16;               // fc1 A-frags: 4096 shorts = 2048 f
constexpr int W2P_OFF = W1P_OFF + 2048;             // fc2 A-frags: 32768 shorts = 16384 f
constexpr int W3P_OFF = W2P_OFF + 16384;            // fc3 A-frags: 32768 shorts

typedef __attribute__((ext_vector_type(8))) short short8;
typedef __attribute__((ext_vector_type(4))) short short4v;
typedef __attribute__((ext_vector_type(4))) float f32x4;
typedef __attribute__((ext_vector_type(2))) unsigned int uint2v;

__device__ __forceinline__ unsigned short f2bf(float x) {  // RNE bf16 (prep only)
    unsigned u = __float_as_uint(x);
    u += 0x7FFF + ((u >> 16) & 1);
    return (unsigned short)(u >> 16);
}

// One-instruction packed f32->bf16 pair (low = a, high = b).
__device__ __forceinline__ unsigned cvt_pk_bf16(float a, float b) {
    unsigned r;
    asm("v_cvt_pk_bf16_f32 %0, %1, %2" : "=v"(r) : "v"(a), "v"(b));
    return r;
}

// quad_perm DPP: lane -> lane^m within each 4-lane quad (VALU, no LDS pipe).
template <int CTRL>
__device__ __forceinline__ float qp(float x) {
    return __int_as_float(__builtin_amdgcn_update_dpp(
        0, __float_as_int(x), CTRL, 0xF, 0xF, true));
}

// ---------------- Kernel 0: all preprocessing (single-bf16 weights) ----------------
// b<96: F tables. b<112: W1p (4096). b<240: W2p (32768). b<368: W3p (32768). b==368: zero.
__global__ void prep_all(const float* __restrict__ emb, const float* __restrict__ w1,
                         const float* __restrict__ fc1_w, const float* __restrict__ fc2_w,
                         const float* __restrict__ fc3_w,
                         float* __restrict__ F, unsigned short* __restrict__ W1p,
                         unsigned short* __restrict__ W2p, unsigned short* __restrict__ W3p,
                         float* __restrict__ rbcp_zero) {
    int b = blockIdx.x;
    if (b < 96) {
        int idx = b * 256 + threadIdx.x;  // 24576
        int i = idx % 48;
        int o = (idx / 48) % 4;
        int node = (idx / 192) % 32;
        int c = idx / 6144;
        float acc = 0.f;
        if (i < 46) {
#pragma unroll
            for (int k = 0; k < 3; k++) acc += w1[(o * 4 + c) * 3 + k] * emb[node * 96 + 2 * i + k];
        }
        F[idx] = acc;
        return;
    }
    if (b < 112) {  // fc1 A-layout, K padded 16->32, single bf16
        int t = (b - 96) * 256 + threadIdx.x;  // 4096
        int j = t & 7, lane = (t >> 3) & 63, mt = t >> 9;
        int k = (lane >> 4) * 8 + j, n = mt * 16 + (lane & 15);
        float w = (k < 16) ? fc1_w[k * 128 + n] : 0.f;
        W1p[t] = f2bf(w);
        return;
    }
    if (b < 240) {  // fc2 A-layout [16mt][4ks], single bf16
        int t = (b - 112) * 256 + threadIdx.x;  // 32768
        int j = t & 7, lane = (t >> 3) & 63, ks = (t >> 9) & 3, mt = t >> 11;
        int k = ks * 32 + (lane >> 4) * 8 + j, n = mt * 16 + (lane & 15);
        W2p[t] = f2bf(fc2_w[k * 256 + n]);
        return;
    }
    if (b < 368) {  // fc3 A-layout [8mt][8ks], single bf16
        int t = (b - 240) * 256 + threadIdx.x;  // 32768
        int j = t & 7, lane = (t >> 3) & 63, ks = (t >> 9) & 7, mt = t >> 12;
        int k = ks * 32 + (lane >> 4) * 8 + j, n = mt * 16 + (lane & 15);
        W3p[t] = f2bf(fc3_w[k * 128 + n]);
        return;
    }
    for (int k = threadIdx.x; k < 2064; k += 256) rbcp_zero[k] = 0.f;  // rbc_part (+legacy)
}

// ---------------- Kernel 1: r8 restructure — fc2 full-K in regs (acc2[4][4]),
// X3-FULL (32KB) overwrites dead X1+X2 regions; 5 barriers instead of 7; fc2/fc3
// are single unbroken 64-MFMA phases.
// Established dead ends (do not retry): multi-chunk loop (spills), min-waves=6
// (VGPR clamp+spill), 64-wide sample quarters (flat), fused prop (+19us),
// one-block-per-pair, DPP-for-shfl (r3: neutral), fc2/fc3 64-col quarters for LDS 24K
// (r4: occupancy unchanged, +5.5us -> NOT LDS-limited), cvt_pk epilogues (r5: -3us),
// batched weight prefetch (r6: compiler re-sank, neutral), counter->extra-kernel
// (r7: -1us, atomic finale was ~1us not 40). ----------------
__global__ __launch_bounds__(256, 4)
void mlp_kernel(const float* __restrict__ F, const int* __restrict__ edges,
                const float* __restrict__ b1v,
                const float* __restrict__ w2, const float* __restrict__ b2,
                const float* __restrict__ w3, const float* __restrict__ b3,
                const float* __restrict__ fc1_b, const float* __restrict__ fc2_b,
                const float* __restrict__ fc3_b,
                const float* __restrict__ fc4_w, const float* __restrict__ fc4_b,
                const unsigned short* __restrict__ W1p, const unsigned short* __restrict__ W2p,
                const unsigned short* __restrict__ W3p,
                float* __restrict__ preds) {
    // LDS (floats): conv/fc1 phase: X1 at [0,512), X2 at [4096,8192).
    // fc3 phase: X3full spans [0,8192) (64 samples x 256 k bf16 = 32KB) — overwrites
    // dead X1+X2 after fc2's reads complete. part at [8192,8448).
    __shared__ __align__(16) float smem[8448];
    unsigned short* X1 = (unsigned short*)smem;
    unsigned short* X3f = (unsigned short*)smem;
    unsigned short* X2 = (unsigned short*)(smem + 4096);
    float* part = smem + 8192;

    const int tid = threadIdx.x;
    const int p = blockIdx.x >> 2;
    const int e0 = (blockIdx.x & 3) * 64;
    const int s = p >> 5, t = p & 31;
    if (s == t) return;

    const int lane = tid & 63, wave = tid >> 6;
    const int mrow = lane & 15, quad = lane >> 4;

    const int gsample = tid >> 2, o = tid & 3;  // conv roles
    float h1[23];
    // ---- conv1: table sum (float4 loads, padded-48 rows), pool THEN relu -> regs ----
    {
        const int e = e0 + gsample;
        const int u = edges[2 * e], v = edges[2 * e + 1];
        const f32x4* F0 = (const f32x4*)(F + ((0 * 32 + s) * 4 + o) * 48);
        const f32x4* F1 = (const f32x4*)(F + ((1 * 32 + t) * 4 + o) * 48);
        const f32x4* F2 = (const f32x4*)(F + ((2 * 32 + u) * 4 + o) * 48);
        const f32x4* F3 = (const f32x4*)(F + ((3 * 32 + v) * 4 + o) * 48);
        const float bb = b1v[o];
        float pre[46];
#pragma unroll
        for (int q = 0; q < 12; q++) {
            f32x4 x = F0[q] + F1[q] + F2[q] + F3[q];
#pragma unroll
            for (int z = 0; z < 4; z++) {
                int i = 4 * q + z;
                if (i < 46) pre[i] = x[z] + bb;
            }
        }
#pragma unroll
        for (int j = 0; j < 23; j++) h1[j] = fmaxf(fmaxf(pre[2 * j], pre[2 * j + 1]), 0.f);
    }
    float h2[10];
    // ---- conv2: cross-channel via DPP quad_perm, sliding ring; pool+relu fused ----
    {
        float wm[4][3];  // wm[m][k] = w2[o][o^m][k]
#pragma unroll
        for (int m = 0; m < 4; m++)
#pragma unroll
            for (int k = 0; k < 3; k++) wm[m][k] = w2[o * 12 + (o ^ m) * 3 + k];
        const float bb = b2[o];
        float win[4][3];
#pragma unroll
        for (int j = 0; j < 2; j++) {
            float x = h1[j];
            win[0][j] = x;
            win[1][j] = qp<0xB1>(x);
            win[2][j] = qp<0x4E>(x);
            win[3][j] = qp<0x1B>(x);
        }
        float pre[20];
#pragma unroll
        for (int i = 0; i < 20; i++) {
            float x = h1[i + 2];
            win[0][(i + 2) % 3] = x;
            win[1][(i + 2) % 3] = qp<0xB1>(x);
            win[2][(i + 2) % 3] = qp<0x4E>(x);
            win[3][(i + 2) % 3] = qp<0x1B>(x);
            float acc = bb;
#pragma unroll
            for (int m = 0; m < 4; m++)
#pragma unroll
                for (int k = 0; k < 3; k++)
                    acc = fmaf(wm[m][k], win[m][(i + k) % 3], acc);
            pre[i] = acc;
        }
#pragma unroll
        for (int j = 0; j < 10; j++) h2[j] = fmaxf(fmaxf(pre[2 * j], pre[2 * j + 1]), 0.f);
    }
    // ---- conv3; pool+relu fused; cvt_pk pack -> X1 (bf16 B-frag layout, K 16 pad 32) ----
    {
        float wm[4][3];
#pragma unroll
        for (int m = 0; m < 4; m++)
#pragma unroll
            for (int k = 0; k < 3; k++) wm[m][k] = w3[o * 12 + (o ^ m) * 3 + k];
        const float bb = b3[o];
        float win[4][3];
#pragma unroll
        for (int j = 0; j < 2; j++) {
            float x = h2[j];
            win[0][j] = x;
            win[1][j] = qp<0xB1>(x);
            win[2][j] = qp<0x4E>(x);
            win[3][j] = qp<0x1B>(x);
        }
        float pre[8];
#pragma unroll
        for (int i = 0; i < 8; i++) {
            float x = h2[i + 2];
            win[0][(i + 2) % 3] = x;
            win[1][(i + 2) % 3] = qp<0xB1>(x);
            win[2][(i + 2) % 3] = qp<0x4E>(x);
            win[3][(i + 2) % 3] = qp<0x1B>(x);
            float acc = bb;
#pragma unroll
            for (int m = 0; m < 4; m++)
#pragma unroll
                for (int k = 0; k < 3; k++)
                    acc = fmaf(wm[m][k], win[m][(i + k) % 3], acc);
            pre[i] = acc;
        }
        float v0 = fmaxf(fmaxf(pre[0], pre[1]), 0.f);
        float v1 = fmaxf(fmaxf(pre[2], pre[3]), 0.f);
        float v2 = fmaxf(fmaxf(pre[4], pre[5]), 0.f);
        float v3 = fmaxf(fmaxf(pre[6], pre[7]), 0.f);
        uint2v d;
        d.x = cvt_pk_bf16(v0, v1);
        d.y = cvt_pk_bf16(v2, v3);
        *(uint2v*)(X1 + (((o >> 1) * 64 + gsample) * 8) + (o & 1) * 4) = d;
        uint2v z2 = (uint2v){0u, 0u};  // k in [16,32) zeros
        *(uint2v*)(X1 + ((((o >> 1) + 2) * 64 + gsample) * 8) + (o & 1) * 4) = z2;
    }
    const short8* W1v = (const short8*)W1p;
    short8 w1f[2];
#pragma unroll
    for (int mtl = 0; mtl < 2; mtl++)
        w1f[mtl] = W1v[(wave * 2 + mtl) * 64 + lane];
    __syncthreads();  // barrier 1: X1 visible
    // ---- fc1 MFMA: A=w1f, B=X1; epilogue -> X2 ----
    {
        short8 bnt[4];
#pragma unroll
        for (int nt = 0; nt < 4; nt++)
            bnt[nt] = *(const short8*)(X1 + (quad * 64 + nt * 16 + mrow) * 8);
        f32x4 acc1[2][4];
#pragma unroll
        for (int a = 0; a < 2; a++)
#pragma unroll
            for (int b = 0; b < 4; b++) acc1[a][b] = (f32x4){0.f, 0.f, 0.f, 0.f};
#pragma unroll
        for (int mtl = 0; mtl < 2; mtl++) {
#pragma unroll
            for (int nt = 0; nt < 4; nt++)
                acc1[mtl][nt] = __builtin_amdgcn_mfma_f32_16x16x32_bf16(w1f[mtl], bnt[nt], acc1[mtl][nt], 0, 0, 0);
        }
#pragma unroll
        for (int mtl = 0; mtl < 2; mtl++) {
            const int mt = wave * 2 + mtl;
            const int n0 = mt * 16 + quad * 4;
            f32x4 b4 = *(const f32x4*)(fc1_b + n0);
#pragma unroll
            for (int nt = 0; nt < 4; nt++) {
                float x0 = fmaxf(acc1[mtl][nt][0] + b4[0], 0.f);
                float x1 = fmaxf(acc1[mtl][nt][1] + b4[1], 0.f);
                float x2 = fmaxf(acc1[mtl][nt][2] + b4[2], 0.f);
                float x3 = fmaxf(acc1[mtl][nt][3] + b4[3], 0.f);
                uint2v d;
                d.x = cvt_pk_bf16(x0, x1);
                d.y = cvt_pk_bf16(x2, x3);
                *(uint2v*)(X2 + ((n0 >> 3) * 64 + nt * 16 + mrow) * 8 + (n0 & 7)) = d;
            }
        }
    }
    __syncthreads();  // barrier 2: X2 ready
    // ---- fc2: full K=128, wave owns 4 of 16 mt (mt = q*4+wave), acc in regs ----
    const short8* W2v = (const short8*)W2p;
    const short8* W3v = (const short8*)W3p;
    f32x4 acc2[4][4];
#pragma unroll
    for (int a = 0; a < 4; a++)
#pragma unroll
        for (int b = 0; b < 4; b++) acc2[a][b] = (f32x4){0.f, 0.f, 0.f, 0.f};
#pragma unroll
    for (int ks = 0; ks < 4; ks++) {
        short8 bfr[4];
#pragma unroll
        for (int nt = 0; nt < 4; nt++)
            bfr[nt] = *(const short8*)(X2 + ((ks * 4 + quad) * 64 + nt * 16 + mrow) * 8);
#pragma unroll
        for (int q = 0; q < 4; q++) {
            const int mt = q * 4 + wave;
            short8 ah = W2v[(mt * 4 + ks) * 64 + lane];
#pragma unroll
            for (int nt = 0; nt < 4; nt++)
                acc2[q][nt] = __builtin_amdgcn_mfma_f32_16x16x32_bf16(ah, bfr[nt], acc2[q][nt], 0, 0, 0);
        }
    }
    __syncthreads();  // barrier 3: all X2 reads done; X1+X2 regions now dead
    // ---- fc2 epilogue -> X3full (32KB over [0,8192) floats) ----
#pragma unroll
    for (int q = 0; q < 4; q++) {
        const int mt = q * 4 + wave;
        const int n0 = mt * 16 + quad * 4;  // = k index in [0,256)
        f32x4 b4 = *(const f32x4*)(fc2_b + n0);
#pragma unroll
        for (int nt = 0; nt < 4; nt++) {
            float x0 = fmaxf(acc2[q][nt][0] + b4[0], 0.f);
            float x1 = fmaxf(acc2[q][nt][1] + b4[1], 0.f);
            float x2 = fmaxf(acc2[q][nt][2] + b4[2], 0.f);
            float x3 = fmaxf(acc2[q][nt][3] + b4[3], 0.f);
            uint2v d;
            d.x = cvt_pk_bf16(x0, x1);
            d.y = cvt_pk_bf16(x2, x3);
            *(uint2v*)(X3f + ((n0 >> 3) * 64 + nt * 16 + mrow) * 8 + (n0 & 7)) = d;
        }
    }
    __syncthreads();  // barrier 4: X3full ready
    // ---- fc3: all 8 k-steps uninterrupted ----
    f32x4 acc3[2][4];
#pragma unroll
    for (int a = 0; a < 2; a++)
#pragma unroll
        for (int b = 0; b < 4; b++) acc3[a][b] = (f32x4){0.f, 0.f, 0.f, 0.f};
#pragma unroll
    for (int ks = 0; ks < 8; ks++) {
        short8 bfr[4];
#pragma unroll
        for (int nt = 0; nt < 4; nt++)
            bfr[nt] = *(const short8*)(X3f + ((ks * 4 + quad) * 64 + nt * 16 + mrow) * 8);
#pragma unroll
        for (int mtl = 0; mtl < 2; mtl++) {
            const int mt = wave * 2 + mtl;
            short8 ah = W3v[(mt * 8 + ks) * 64 + lane];
#pragma unroll
            for (int nt = 0; nt < 4; nt++)
                acc3[mtl][nt] = __builtin_amdgcn_mfma_f32_16x16x32_bf16(ah, bfr[nt], acc3[mtl][nt], 0, 0, 0);
        }
    }
    // ---- fused fc4 ----
    {
        float p4[4] = {0.f, 0.f, 0.f, 0.f};
#pragma unroll
        for (int mtl = 0; mtl < 2; mtl++) {
            const int mt = wave * 2 + mtl;
            const int n0 = mt * 16 + quad * 4;
            f32x4 b4 = *(const f32x4*)(fc3_b + n0);
            f32x4 w44 = *(const f32x4*)(fc4_w + n0);
#pragma unroll
            for (int nt = 0; nt < 4; nt++)
#pragma unroll
                for (int r = 0; r < 4; r++)
                    p4[nt] = fmaf(fmaxf(acc3[mtl][nt][r] + b4[r], 0.f), w44[r], p4[nt]);
        }
#pragma unroll
        for (int nt = 0; nt < 4; nt++) {
            p4[nt] += __shfl_xor(p4[nt], 16, 64);
            p4[nt] += __shfl_xor(p4[nt], 32, 64);
        }
        if (quad == 0) {
#pragma unroll
            for (int nt = 0; nt < 4; nt++)
                part[wave * 64 + nt * 16 + mrow] = p4[nt];
        }
    }
    __syncthreads();  // barrier 5: part ready
    if (tid < 64) {
        float pred = part[tid] + part[64 + tid] + part[128 + tid] + part[192 + tid] + fc4_b[0];
        preds[p * 256 + e0 + tid] = pred;
    }
}

// ---------------- Kernel 2: propagation only, one WAVE per pair (256 blocks). ----------------
__global__ __launch_bounds__(256)
void prop_kernel(const int* __restrict__ edges, const float* __restrict__ preds,
                 float* __restrict__ rbc_part) {
    const int tid = threadIdx.x;
    const int wave = tid >> 6, lane = tid & 63;
    const int p = blockIdx.x * 4 + wave;
    const int s = p >> 5, t = p & 31;
    __shared__ float xw[4][32], xnw[4][32], raccw[4][32];
    int u[4], v[4];
    float pr[4];
#pragma unroll
    for (int j = 0; j < 4; j++) {
        int e = lane + 64 * j;
        u[j] = edges[2 * e];
        v[j] = edges[2 * e + 1];
        pr[j] = preds[p * 256 + e];
    }
    if (lane < 32) { xw[wave][lane] = (lane == s) ? 1.f : 0.f; raccw[wave][lane] = 0.f; }
    const bool active = (s != t);
    for (int step = 0; step < 3; step++) {
        if (lane < 32) xnw[wave][lane] = 0.f;
        __syncthreads();
        if (active) {
#pragma unroll
            for (int j = 0; j < 4; j++)
                atomicAdd(&xnw[wave][v[j]], xw[wave][u[j]] * pr[j]);
        }
        __syncthreads();
        if (lane < 32) { raccw[wave][lane] += xnw[wave][lane]; xw[wave][lane] = xnw[wave][lane]; }
        __syncthreads();
    }
    if (active && lane < 32) atomicAdd(&rbc_part[(p & 63) * 32 + lane], raccw[wave][lane]);
}

// ---------------- Kernel 3: final reduce + normalize (1 block). ----------------
__global__ __launch_bounds__(256)
void norm_kernel(const float* __restrict__ rbc_part, float* __restrict__ out) {
    const int tid = threadIdx.x;
    const int node = tid & 31, sub = tid >> 5;
    __shared__ float red[8][32];
    float vv = 0.f;
#pragma unroll
    for (int g = 0; g < 8; g++)
        vv += rbc_part[(sub * 8 + g) * 32 + node];
    red[sub][node] = vv;
    __syncthreads();
    if (tid < 32) {
        float acc = 0.f;
#pragma unroll
        for (int sb = 0; sb < 8; sb++) acc += red[sb][tid];
        float tot = acc;
#pragma unroll
        for (int mask = 1; mask < 32; mask <<= 1) tot += __shfl_xor(tot, mask, 32);
        out[tid] = acc / tot;
    }
}

extern "C" void kernel_launch(void* const* d_in, const int* in_sizes, int n_in,
                              void* d_out, int out_size, void* d_ws, size_t ws_size,
                              hipStream_t stream) {
    const float* emb = (const float*)d_in[0];
    const int* edges = (const int*)d_in[1];
    const float* w1 = (const float*)d_in[2];
    const float* b1 = (const float*)d_in[3];
    const float* w2 = (const float*)d_in[4];
    const float* b2 = (const float*)d_in[5];
    const float* w3 = (const float*)d_in[6];
    const float* b3 = (const float*)d_in[7];
    const float* fc1_w = (const float*)d_in[8];
    const float* fc1_b = (const float*)d_in[9];
    const float* fc2_w = (const float*)d_in[10];
    const float* fc2_b = (const float*)d_in[11];
    const float* fc3_w = (const float*)d_in[12];
    const float* fc3_b = (const float*)d_in[13];
    const float* fc4_w = (const float*)d_in[14];
    const float* fc4_b = (const float*)d_in[15];

    float* ws = (float*)d_ws;
    float* F = ws;
    float* preds = ws + PREDS_OFF;
    float* rbc_part = ws + RBCP_OFF;
    unsigned short* W1p = (unsigned short*)(ws + W1P_OFF);
    unsigned short* W2p = (unsigned short*)(ws + W2P_OFF);
    unsigned short* W3p = (unsigned short*)(ws + W3P_OFF);
    float* out = (float*)d_out;

    prep_all<<<dim3(369), dim3(256), 0, stream>>>(emb, w1, fc1_w, fc2_w, fc3_w,
                                                  F, W1p, W2p, W3p, rbc_part);
    mlp_kernel<<<dim3(4096), dim3(256), 0, stream>>>(
        F, edges, b1, w2, b2, w3, b3, fc1_b, fc2_b, fc3_b,
        fc4_w, fc4_b, W1p, W2p, W3p, preds);
    prop_kernel<<<dim3(256), dim3(256), 0, stream>>>(edges, preds, rbc_part);
    norm_kernel<<<dim3(1), dim3(256), 0, stream>>>(rbc_part, out);
}

// Round 9
// 149.261 us; speedup vs baseline: 1.1789x; 1.0936x over previous
//
#include <hip/hip_runtime.h>

// ---- ws layout (float offsets) ----
// G: per-pair conv1 tables [1024][4][48] (F_s + F_t)           = 196608 floats
// H: per-edge conv1 tables [256][4][48]  (F_u + F_v + b1)      = 49152 floats
constexpr int G_OFF = 0;
constexpr int H_OFF = 196608;
constexpr int PREDS_OFF = H_OFF + 49152;        // 245760
constexpr int RBCP_OFF = PREDS_OFF + 262144;    // 507904: rbc_part[64][32]
constexpr int CNT_OFF = RBCP_OFF + 2048;        // 509952 (legacy pad)
constexpr int W1P_OFF = CNT_OFF + 16;           // 509968: fc1 A-frags 4096 shorts
constexpr int W2P_OFF = W1P_OFF + 2048;         // 512016: fc2 A-frags 32768 shorts
constexpr int W3P_OFF = W2P_OFF + 16384;        // 528400: fc3 A-frags 32768 shorts
// total = 544784 floats — identical footprint to the r8 layout (verified).

typedef __attribute__((ext_vector_type(8))) short short8;
typedef __attribute__((ext_vector_type(4))) short short4v;
typedef __attribute__((ext_vector_type(4))) float f32x4;
typedef __attribute__((ext_vector_type(2))) unsigned int uint2v;

__device__ __forceinline__ unsigned short f2bf(float x) {  // RNE bf16 (prep only)
    unsigned u = __float_as_uint(x);
    u += 0x7FFF + ((u >> 16) & 1);
    return (unsigned short)(u >> 16);
}

// One-instruction packed f32->bf16 pair (low = a, high = b).
__device__ __forceinline__ unsigned cvt_pk_bf16(float a, float b) {
    unsigned r;
    asm("v_cvt_pk_bf16_f32 %0, %1, %2" : "=v"(r) : "v"(a), "v"(b));
    return r;
}

// quad_perm DPP: lane -> lane^m within each 4-lane quad (VALU, no LDS pipe).
template <int CTRL>
__device__ __forceinline__ float qp(float x) {
    return __int_as_float(__builtin_amdgcn_update_dpp(
        0, __float_as_int(x), CTRL, 0xF, 0xF, true));
}

// ---------------- Kernel 0: all preprocessing ----------------
// b<768: G (pair tables, F_s+F_t). b<960: H (edge tables, F_u+F_v+b1).
// b<976: W1p. b<1104: W2p. b<1232: W3p. b==1232: zero rbc_part.
__global__ void prep_all(const float* __restrict__ emb, const int* __restrict__ edges,
                         const float* __restrict__ w1, const float* __restrict__ b1,
                         const float* __restrict__ fc1_w, const float* __restrict__ fc2_w,
                         const float* __restrict__ fc3_w,
                         float* __restrict__ G, float* __restrict__ H,
                         unsigned short* __restrict__ W1p,
                         unsigned short* __restrict__ W2p, unsigned short* __restrict__ W3p,
                         float* __restrict__ rbcp_zero) {
    int b = blockIdx.x;
    if (b < 768) {  // G[p][o][i] = conv1 contribution of (s as c0) + (t as c1)
        int idx = b * 256 + threadIdx.x;  // 196608
        int i = idx % 48;
        int o = (idx / 48) & 3;
        int p = idx / 192;
        int s = p >> 5, t = p & 31;
        float acc = 0.f;
        if (i < 46) {
#pragma unroll
            for (int k = 0; k < 3; k++)
                acc += w1[(o * 4 + 0) * 3 + k] * emb[s * 96 + 2 * i + k] +
                       w1[(o * 4 + 1) * 3 + k] * emb[t * 96 + 2 * i + k];
        }
        G[idx] = acc;
        return;
    }
    if (b < 960) {  // H[e][o][i] = conv1 contribution of (u as c2) + (v as c3) + b1[o]
        int idx = (b - 768) * 256 + threadIdx.x;  // 49152
        int i = idx % 48;
        int o = (idx / 48) & 3;
        int e = idx / 192;
        int u = edges[2 * e], v = edges[2 * e + 1];
        float acc = 0.f;
        if (i < 46) {
            acc = b1[o];
#pragma unroll
            for (int k = 0; k < 3; k++)
                acc += w1[(o * 4 + 2) * 3 + k] * emb[u * 96 + 2 * i + k] +
                       w1[(o * 4 + 3) * 3 + k] * emb[v * 96 + 2 * i + k];
        }
        H[idx] = acc;
        return;
    }
    if (b < 976) {  // fc1 A-layout, K padded 16->32, single bf16
        int t = (b - 960) * 256 + threadIdx.x;  // 4096
        int j = t & 7, lane = (t >> 3) & 63, mt = t >> 9;
        int k = (lane >> 4) * 8 + j, n = mt * 16 + (lane & 15);
        float w = (k < 16) ? fc1_w[k * 128 + n] : 0.f;
        W1p[t] = f2bf(w);
        return;
    }
    if (b < 1104) {  // fc2 A-layout [16mt][4ks], single bf16
        int t = (b - 976) * 256 + threadIdx.x;  // 32768
        int j = t & 7, lane = (t >> 3) & 63, ks = (t >> 9) & 3, mt = t >> 11;
        int k = ks * 32 + (lane >> 4) * 8 + j, n = mt * 16 + (lane & 15);
        W2p[t] = f2bf(fc2_w[k * 256 + n]);
        return;
    }
    if (b < 1232) {  // fc3 A-layout [8mt][8ks], single bf16
        int t = (b - 1104) * 256 + threadIdx.x;  // 32768
        int j = t & 7, lane = (t >> 3) & 63, ks = (t >> 9) & 7, mt = t >> 12;
        int k = ks * 32 + (lane >> 4) * 8 + j, n = mt * 16 + (lane & 15);
        W3p[t] = f2bf(fc3_w[k * 128 + n]);
        return;
    }
    for (int k = threadIdx.x; k < 2064; k += 256) rbcp_zero[k] = 0.f;  // rbc_part (+legacy)
}

// ---------------- Kernel 1: r8 structure + G/H conv1 split (half the conv1 loads
// and adds; bias folded into H; edges gather removed from hot kernel).
// Established dead ends (do not retry): multi-chunk loop (spills), min-waves=6
// (VGPR clamp+spill), 64-wide sample quarters (flat), fused prop (+19us),
// one-block-per-pair, DPP-for-shfl (r3: neutral), fc2/fc3 64-col quarters
// (r4: occupancy unchanged -> reg-file-limited, AGPR+VGPR~128), cvt_pk epilogues
// (r5: -3us), batched weight prefetch (r6: compiler re-sank, neutral),
// counter->extra-kernel (r7: -1us), 5-barrier X3full (r8: neutral). ----------------
__global__ __launch_bounds__(256, 4)
void mlp_kernel(const float* __restrict__ G, const float* __restrict__ H,
                const float* __restrict__ w2, const float* __restrict__ b2,
                const float* __restrict__ w3, const float* __restrict__ b3,
                const float* __restrict__ fc1_b, const float* __restrict__ fc2_b,
                const float* __restrict__ fc3_b,
                const float* __restrict__ fc4_w, const float* __restrict__ fc4_b,
                const unsigned short* __restrict__ W1p, const unsigned short* __restrict__ W2p,
                const unsigned short* __restrict__ W3p,
                float* __restrict__ preds) {
    // LDS (floats): conv/fc1 phase: X1 at [0,512), X2 at [4096,8192).
    // fc3 phase: X3full spans [0,8192) — overwrites dead X1+X2 after fc2's reads.
    // part at [8192,8448).
    __shared__ __align__(16) float smem[8448];
    unsigned short* X1 = (unsigned short*)smem;
    unsigned short* X3f = (unsigned short*)smem;
    unsigned short* X2 = (unsigned short*)(smem + 4096);
    float* part = smem + 8192;

    const int tid = threadIdx.x;
    const int p = blockIdx.x >> 2;
    const int e0 = (blockIdx.x & 3) * 64;
    const int s = p >> 5, t = p & 31;
    if (s == t) return;

    const int lane = tid & 63, wave = tid >> 6;
    const int mrow = lane & 15, quad = lane >> 4;

    const int gsample = tid >> 2, o = tid & 3;  // conv roles
    float h1[23];
    // ---- conv1: G[p]+H[e] (bias pre-folded), pool THEN relu -> regs ----
    {
        const int e = e0 + gsample;
        const f32x4* Gp = (const f32x4*)(G + (p * 4 + o) * 48);
        const f32x4* Hp = (const f32x4*)(H + (e * 4 + o) * 48);
        float pre[46];
#pragma unroll
        for (int q = 0; q < 12; q++) {
            f32x4 x = Gp[q] + Hp[q];
#pragma unroll
            for (int z = 0; z < 4; z++) {
                int i = 4 * q + z;
                if (i < 46) pre[i] = x[z];
            }
        }
#pragma unroll
        for (int j = 0; j < 23; j++) h1[j] = fmaxf(fmaxf(pre[2 * j], pre[2 * j + 1]), 0.f);
    }
    float h2[10];
    // ---- conv2: cross-channel via DPP quad_perm, sliding ring; pool+relu fused ----
    {
        float wm[4][3];  // wm[m][k] = w2[o][o^m][k]
#pragma unroll
        for (int m = 0; m < 4; m++)
#pragma unroll
            for (int k = 0; k < 3; k++) wm[m][k] = w2[o * 12 + (o ^ m) * 3 + k];
        const float bb = b2[o];
        float win[4][3];
#pragma unroll
        for (int j = 0; j < 2; j++) {
            float x = h1[j];
            win[0][j] = x;
            win[1][j] = qp<0xB1>(x);
            win[2][j] = qp<0x4E>(x);
            win[3][j] = qp<0x1B>(x);
        }
        float pre[20];
#pragma unroll
        for (int i = 0; i < 20; i++) {
            float x = h1[i + 2];
            win[0][(i + 2) % 3] = x;
            win[1][(i + 2) % 3] = qp<0xB1>(x);
            win[2][(i + 2) % 3] = qp<0x4E>(x);
            win[3][(i + 2) % 3] = qp<0x1B>(x);
            float acc = bb;
#pragma unroll
            for (int m = 0; m < 4; m++)
#pragma unroll
                for (int k = 0; k < 3; k++)
                    acc = fmaf(wm[m][k], win[m][(i + k) % 3], acc);
            pre[i] = acc;
        }
#pragma unroll
        for (int j = 0; j < 10; j++) h2[j] = fmaxf(fmaxf(pre[2 * j], pre[2 * j + 1]), 0.f);
    }
    // ---- conv3; pool+relu fused; cvt_pk pack -> X1 (bf16 B-frag layout, K 16 pad 32) ----
    {
        float wm[4][3];
#pragma unroll
        for (int m = 0; m < 4; m++)
#pragma unroll
            for (int k = 0; k < 3; k++) wm[m][k] = w3[o * 12 + (o ^ m) * 3 + k];
        const float bb = b3[o];
        float win[4][3];
#pragma unroll
        for (int j = 0; j < 2; j++) {
            float x = h2[j];
            win[0][j] = x;
            win[1][j] = qp<0xB1>(x);
            win[2][j] = qp<0x4E>(x);
            win[3][j] = qp<0x1B>(x);
        }
        float pre[8];
#pragma unroll
        for (int i = 0; i < 8; i++) {
            float x = h2[i + 2];
            win[0][(i + 2) % 3] = x;
            win[1][(i + 2) % 3] = qp<0xB1>(x);
            win[2][(i + 2) % 3] = qp<0x4E>(x);
            win[3][(i + 2) % 3] = qp<0x1B>(x);
            float acc = bb;
#pragma unroll
            for (int m = 0; m < 4; m++)
#pragma unroll
                for (int k = 0; k < 3; k++)
                    acc = fmaf(wm[m][k], win[m][(i + k) % 3], acc);
            pre[i] = acc;
        }
        float v0 = fmaxf(fmaxf(pre[0], pre[1]), 0.f);
        float v1 = fmaxf(fmaxf(pre[2], pre[3]), 0.f);
        float v2 = fmaxf(fmaxf(pre[4], pre[5]), 0.f);
        float v3 = fmaxf(fmaxf(pre[6], pre[7]), 0.f);
        uint2v d;
        d.x = cvt_pk_bf16(v0, v1);
        d.y = cvt_pk_bf16(v2, v3);
        *(uint2v*)(X1 + (((o >> 1) * 64 + gsample) * 8) + (o & 1) * 4) = d;
        uint2v z2 = (uint2v){0u, 0u};  // k in [16,32) zeros
        *(uint2v*)(X1 + ((((o >> 1) + 2) * 64 + gsample) * 8) + (o & 1) * 4) = z2;
    }
    const short8* W1v = (const short8*)W1p;
    short8 w1f[2];
#pragma unroll
    for (int mtl = 0; mtl < 2; mtl++)
        w1f[mtl] = W1v[(wave * 2 + mtl) * 64 + lane];
    __syncthreads();  // barrier 1: X1 visible
    // ---- fc1 MFMA: A=w1f, B=X1; epilogue -> X2 ----
    {
        short8 bnt[4];
#pragma unroll
        for (int nt = 0; nt < 4; nt++)
            bnt[nt] = *(const short8*)(X1 + (quad * 64 + nt * 16 + mrow) * 8);
        f32x4 acc1[2][4];
#pragma unroll
        for (int a = 0; a < 2; a++)
#pragma unroll
            for (int b = 0; b < 4; b++) acc1[a][b] = (f32x4){0.f, 0.f, 0.f, 0.f};
#pragma unroll
        for (int mtl = 0; mtl < 2; mtl++) {
#pragma unroll
            for (int nt = 0; nt < 4; nt++)
                acc1[mtl][nt] = __builtin_amdgcn_mfma_f32_16x16x32_bf16(w1f[mtl], bnt[nt], acc1[mtl][nt], 0, 0, 0);
        }
#pragma unroll
        for (int mtl = 0; mtl < 2; mtl++) {
            const int mt = wave * 2 + mtl;
            const int n0 = mt * 16 + quad * 4;
            f32x4 b4 = *(const f32x4*)(fc1_b + n0);
#pragma unroll
            for (int nt = 0; nt < 4; nt++) {
                float x0 = fmaxf(acc1[mtl][nt][0] + b4[0], 0.f);
                float x1 = fmaxf(acc1[mtl][nt][1] + b4[1], 0.f);
                float x2 = fmaxf(acc1[mtl][nt][2] + b4[2], 0.f);
                float x3 = fmaxf(acc1[mtl][nt][3] + b4[3], 0.f);
                uint2v d;
                d.x = cvt_pk_bf16(x0, x1);
                d.y = cvt_pk_bf16(x2, x3);
                *(uint2v*)(X2 + ((n0 >> 3) * 64 + nt * 16 + mrow) * 8 + (n0 & 7)) = d;
            }
        }
    }
    __syncthreads();  // barrier 2: X2 ready
    // ---- fc2: full K=128, wave owns 4 of 16 mt (mt = q*4+wave), acc in regs ----
    const short8* W2v = (const short8*)W2p;
    const short8* W3v = (const short8*)W3p;
    f32x4 acc2[4][4];
#pragma unroll
    for (int a = 0; a < 4; a++)
#pragma unroll
        for (int b = 0; b < 4; b++) acc2[a][b] = (f32x4){0.f, 0.f, 0.f, 0.f};
#pragma unroll
    for (int ks = 0; ks < 4; ks++) {
        short8 bfr[4];
#pragma unroll
        for (int nt = 0; nt < 4; nt++)
            bfr[nt] = *(const short8*)(X2 + ((ks * 4 + quad) * 64 + nt * 16 + mrow) * 8);
#pragma unroll
        for (int q = 0; q < 4; q++) {
            const int mt = q * 4 + wave;
            short8 ah = W2v[(mt * 4 + ks) * 64 + lane];
#pragma unroll
            for (int nt = 0; nt < 4; nt++)
                acc2[q][nt] = __builtin_amdgcn_mfma_f32_16x16x32_bf16(ah, bfr[nt], acc2[q][nt], 0, 0, 0);
        }
    }
    __syncthreads();  // barrier 3: all X2 reads done; X1+X2 regions now dead
    // ---- fc2 epilogue -> X3full (32KB over [0,8192) floats) ----
#pragma unroll
    for (int q = 0; q < 4; q++) {
        const int mt = q * 4 + wave;
        const int n0 = mt * 16 + quad * 4;  // = k index in [0,256)
        f32x4 b4 = *(const f32x4*)(fc2_b + n0);
#pragma unroll
        for (int nt = 0; nt < 4; nt++) {
            float x0 = fmaxf(acc2[q][nt][0] + b4[0], 0.f);
            float x1 = fmaxf(acc2[q][nt][1] + b4[1], 0.f);
            float x2 = fmaxf(acc2[q][nt][2] + b4[2], 0.f);
            float x3 = fmaxf(acc2[q][nt][3] + b4[3], 0.f);
            uint2v d;
            d.x = cvt_pk_bf16(x0, x1);
            d.y = cvt_pk_bf16(x2, x3);
            *(uint2v*)(X3f + ((n0 >> 3) * 64 + nt * 16 + mrow) * 8 + (n0 & 7)) = d;
        }
    }
    __syncthreads();  // barrier 4: X3full ready
    // ---- fc3: all 8 k-steps uninterrupted ----
    f32x4 acc3[2][4];
#pragma unroll
    for (int a = 0; a < 2; a++)
#pragma unroll
        for (int b = 0; b < 4; b++) acc3[a][b] = (f32x4){0.f, 0.f, 0.f, 0.f};
#pragma unroll
    for (int ks = 0; ks < 8; ks++) {
        short8 bfr[4];
#pragma unroll
        for (int nt = 0; nt < 4; nt++)
            bfr[nt] = *(const short8*)(X3f + ((ks * 4 + quad) * 64 + nt * 16 + mrow) * 8);
#pragma unroll
        for (int mtl = 0; mtl < 2; mtl++) {
            const int mt = wave * 2 + mtl;
            short8 ah = W3v[(mt * 8 + ks) * 64 + lane];
#pragma unroll
            for (int nt = 0; nt < 4; nt++)
                acc3[mtl][nt] = __builtin_amdgcn_mfma_f32_16x16x32_bf16(ah, bfr[nt], acc3[mtl][nt], 0, 0, 0);
        }
    }
    // ---- fused fc4 ----
    {
        float p4[4] = {0.f, 0.f, 0.f, 0.f};
#pragma unroll
        for (int mtl = 0; mtl < 2; mtl++) {
            const int mt = wave * 2 + mtl;
            const int n0 = mt * 16 + quad * 4;
            f32x4 b4 = *(const f32x4*)(fc3_b + n0);
            f32x4 w44 = *(const f32x4*)(fc4_w + n0);
#pragma unroll
            for (int nt = 0; nt < 4; nt++)
#pragma unroll
                for (int r = 0; r < 4; r++)
                    p4[nt] = fmaf(fmaxf(acc3[mtl][nt][r] + b4[r], 0.f), w44[r], p4[nt]);
        }
#pragma unroll
        for (int nt = 0; nt < 4; nt++) {
            p4[nt] += __shfl_xor(p4[nt], 16, 64);
            p4[nt] += __shfl_xor(p4[nt], 32, 64);
        }
        if (quad == 0) {
#pragma unroll
            for (int nt = 0; nt < 4; nt++)
                part[wave * 64 + nt * 16 + mrow] = p4[nt];
        }
    }
    __syncthreads();  // barrier 5: part ready
    if (tid < 64) {
        float pred = part[tid] + part[64 + tid] + part[128 + tid] + part[192 + tid] + fc4_b[0];
        preds[p * 256 + e0 + tid] = pred;
    }
}

// ---------------- Kernel 2: propagation only, one WAVE per pair (256 blocks). ----------------
__global__ __launch_bounds__(256)
void prop_kernel(const int* __restrict__ edges, const float* __restrict__ preds,
                 float* __restrict__ rbc_part) {
    const int tid = threadIdx.x;
    const int wave = tid >> 6, lane = tid & 63;
    const int p = blockIdx.x * 4 + wave;
    const int s = p >> 5, t = p & 31;
    __shared__ float xw[4][32], xnw[4][32], raccw[4][32];
    int u[4], v[4];
    float pr[4];
#pragma unroll
    for (int j = 0; j < 4; j++) {
        int e = lane + 64 * j;
        u[j] = edges[2 * e];
        v[j] = edges[2 * e + 1];
        pr[j] = preds[p * 256 + e];
    }
    if (lane < 32) { xw[wave][lane] = (lane == s) ? 1.f : 0.f; raccw[wave][lane] = 0.f; }
    const bool active = (s != t);
    for (int step = 0; step < 3; step++) {
        if (lane < 32) xnw[wave][lane] = 0.f;
        __syncthreads();
        if (active) {
#pragma unroll
            for (int j = 0; j < 4; j++)
                atomicAdd(&xnw[wave][v[j]], xw[wave][u[j]] * pr[j]);
        }
        __syncthreads();
        if (lane < 32) { raccw[wave][lane] += xnw[wave][lane]; xw[wave][lane] = xnw[wave][lane]; }
        __syncthreads();
    }
    if (active && lane < 32) atomicAdd(&rbc_part[(p & 63) * 32 + lane], raccw[wave][lane]);
}

// ---------------- Kernel 3: final reduce + normalize (1 block). ----------------
__global__ __launch_bounds__(256)
void norm_kernel(const float* __restrict__ rbc_part, float* __restrict__ out) {
    const int tid = threadIdx.x;
    const int node = tid & 31, sub = tid >> 5;
    __shared__ float red[8][32];
    float vv = 0.f;
#pragma unroll
    for (int g = 0; g < 8; g++)
        vv += rbc_part[(sub * 8 + g) * 32 + node];
    red[sub][node] = vv;
    __syncthreads();
    if (tid < 32) {
        float acc = 0.f;
#pragma unroll
        for (int sb = 0; sb < 8; sb++) acc += red[sb][tid];
        float tot = acc;
#pragma unroll
        for (int mask = 1; mask < 32; mask <<= 1) tot += __shfl_xor(tot, mask, 32);
        out[tid] = acc / tot;
    }
}

extern "C" void kernel_launch(void* const* d_in, const int* in_sizes, int n_in,
                              void* d_out, int out_size, void* d_ws, size_t ws_size,
                              hipStream_t stream) {
    const float* emb = (const float*)d_in[0];
    const int* edges = (const int*)d_in[1];
    const float* w1 = (const float*)d_in[2];
    const float* b1 = (const float*)d_in[3];
    const float* w2 = (const float*)d_in[4];
    const float* b2 = (const float*)d_in[5];
    const float* w3 = (const float*)d_in[6];
    const float* b3 = (const float*)d_in[7];
    const float* fc1_w = (const float*)d_in[8];
    const float* fc1_b = (const float*)d_in[9];
    const float* fc2_w = (const float*)d_in[10];
    const float* fc2_b = (const float*)d_in[11];
    const float* fc3_w = (const float*)d_in[12];
    const float* fc3_b = (const float*)d_in[13];
    const float* fc4_w = (const float*)d_in[14];
    const float* fc4_b = (const float*)d_in[15];

    float* ws = (float*)d_ws;
    float* G = ws + G_OFF;
    float* H = ws + H_OFF;
    float* preds = ws + PREDS_OFF;
    float* rbc_part = ws + RBCP_OFF;
    unsigned short* W1p = (unsigned short*)(ws + W1P_OFF);
    unsigned short* W2p = (unsigned short*)(ws + W2P_OFF);
    unsigned short* W3p = (unsigned short*)(ws + W3P_OFF);
    float* out = (float*)d_out;

    prep_all<<<dim3(1233), dim3(256), 0, stream>>>(emb, edges, w1, b1, fc1_w, fc2_w, fc3_w,
                                                   G, H, W1p, W2p, W3p, rbc_part);
    mlp_kernel<<<dim3(4096), dim3(256), 0, stream>>>(
        G, H, w2, b2, w3, b3, fc1_b, fc2_b, fc3_b,
        fc4_w, fc4_b, W1p, W2p, W3p, preds);
    prop_kernel<<<dim3(256), dim3(256), 0, stream>>>(edges, preds, rbc_part);
    norm_kernel<<<dim3(1), dim3(256), 0, stream>>>(rbc_part, out);
}

// Round 10
// 148.651 us; speedup vs baseline: 1.1838x; 1.0041x over previous
//
#include <hip/hip_runtime.h>

// ---- ws layout (float offsets) ----
// G: per-pair conv1 tables [1024][4][48] (F_s + F_t)           = 196608 floats
// H: per-edge conv1 tables [256][4][48]  (F_u + F_v + b1)      = 49152 floats
constexpr int G_OFF = 0;
constexpr int H_OFF = 196608;
constexpr int PREDS_OFF = H_OFF + 49152;        // 245760
constexpr int RBCP_OFF = PREDS_OFF + 262144;    // 507904: rbc_part[64][32]
constexpr int CNT_OFF = RBCP_OFF + 2048;        // 509952 (legacy pad)
constexpr int W1P_OFF = CNT_OFF + 16;           // 509968: fc1 A-frags 4096 shorts
constexpr int W2P_OFF = W1P_OFF + 2048;         // 512016: fc2 A-frags 32768 shorts
constexpr int W3P_OFF = W2P_OFF + 16384;        // 528400: fc3 A-frags 32768 shorts

typedef __attribute__((ext_vector_type(8))) short short8;
typedef __attribute__((ext_vector_type(4))) short short4v;
typedef __attribute__((ext_vector_type(4))) float f32x4;
typedef __attribute__((ext_vector_type(2))) unsigned int uint2v;

__device__ __forceinline__ unsigned short f2bf(float x) {  // RNE bf16 (prep only)
    unsigned u = __float_as_uint(x);
    u += 0x7FFF + ((u >> 16) & 1);
    return (unsigned short)(u >> 16);
}

// One-instruction packed f32->bf16 pair (low = a, high = b).
__device__ __forceinline__ unsigned cvt_pk_bf16(float a, float b) {
    unsigned r;
    asm("v_cvt_pk_bf16_f32 %0, %1, %2" : "=v"(r) : "v"(a), "v"(b));
    return r;
}

// quad_perm DPP: lane -> lane^m within each 4-lane quad (VALU, no LDS pipe).
template <int CTRL>
__device__ __forceinline__ float qp(float x) {
    return __int_as_float(__builtin_amdgcn_update_dpp(
        0, __float_as_int(x), CTRL, 0xF, 0xF, true));
}

// ---------------- Kernel 0: all preprocessing ----------------
// b<768: G (pair tables, F_s+F_t). b<960: H (edge tables, F_u+F_v+b1).
// b<976: W1p. b<1104: W2p. b<1232: W3p. b==1232: zero rbc_part.
__global__ void prep_all(const float* __restrict__ emb, const int* __restrict__ edges,
                         const float* __restrict__ w1, const float* __restrict__ b1,
                         const float* __restrict__ fc1_w, const float* __restrict__ fc2_w,
                         const float* __restrict__ fc3_w,
                         float* __restrict__ G, float* __restrict__ H,
                         unsigned short* __restrict__ W1p,
                         unsigned short* __restrict__ W2p, unsigned short* __restrict__ W3p,
                         float* __restrict__ rbcp_zero) {
    int b = blockIdx.x;
    if (b < 768) {  // G[p][o][i] = conv1 contribution of (s as c0) + (t as c1)
        int idx = b * 256 + threadIdx.x;  // 196608
        int i = idx % 48;
        int o = (idx / 48) & 3;
        int p = idx / 192;
        int s = p >> 5, t = p & 31;
        float acc = 0.f;
        if (i < 46) {
#pragma unroll
            for (int k = 0; k < 3; k++)
                acc += w1[(o * 4 + 0) * 3 + k] * emb[s * 96 + 2 * i + k] +
                       w1[(o * 4 + 1) * 3 + k] * emb[t * 96 + 2 * i + k];
        }
        G[idx] = acc;
        return;
    }
    if (b < 960) {  // H[e][o][i] = conv1 contribution of (u as c2) + (v as c3) + b1[o]
        int idx = (b - 768) * 256 + threadIdx.x;  // 49152
        int i = idx % 48;
        int o = (idx / 48) & 3;
        int e = idx / 192;
        int u = edges[2 * e], v = edges[2 * e + 1];
        float acc = 0.f;
        if (i < 46) {
            acc = b1[o];
#pragma unroll
            for (int k = 0; k < 3; k++)
                acc += w1[(o * 4 + 2) * 3 + k] * emb[u * 96 + 2 * i + k] +
                       w1[(o * 4 + 3) * 3 + k] * emb[v * 96 + 2 * i + k];
        }
        H[idx] = acc;
        return;
    }
    if (b < 976) {  // fc1 A-layout, K padded 16->32, single bf16
        int t = (b - 960) * 256 + threadIdx.x;  // 4096
        int j = t & 7, lane = (t >> 3) & 63, mt = t >> 9;
        int k = (lane >> 4) * 8 + j, n = mt * 16 + (lane & 15);
        float w = (k < 16) ? fc1_w[k * 128 + n] : 0.f;
        W1p[t] = f2bf(w);
        return;
    }
    if (b < 1104) {  // fc2 A-layout [16mt][4ks], single bf16
        int t = (b - 976) * 256 + threadIdx.x;  // 32768
        int j = t & 7, lane = (t >> 3) & 63, ks = (t >> 9) & 3, mt = t >> 11;
        int k = ks * 32 + (lane >> 4) * 8 + j, n = mt * 16 + (lane & 15);
        W2p[t] = f2bf(fc2_w[k * 256 + n]);
        return;
    }
    if (b < 1232) {  // fc3 A-layout [8mt][8ks], single bf16
        int t = (b - 1104) * 256 + threadIdx.x;  // 32768
        int j = t & 7, lane = (t >> 3) & 63, ks = (t >> 9) & 7, mt = t >> 12;
        int k = ks * 32 + (lane >> 4) * 8 + j, n = mt * 16 + (lane & 15);
        W3p[t] = f2bf(fc3_w[k * 128 + n]);
        return;
    }
    for (int k = threadIdx.x; k < 2064; k += 256) rbcp_zero[k] = 0.f;  // rbc_part (+legacy)
}

// ---------------- Kernel 1: r9 + XCD-aware block swizzle (T1). Pair p's 4 sibling
// blocks land on ONE XCD; each XCD owns a contiguous 128-pair G slice (98KB,
// L2-resident) -> G L2-miss count drops ~4x. Bijective: 4096 % 8 == 0.
// Established dead ends (do not retry): multi-chunk loop (spills), min-waves>=5
// (VGPR clamp+spill), 64-wide sample quarters (flat), fused prop (+19us),
// one-block-per-pair, DPP-for-shfl (r3: neutral), fc2/fc3 64-col quarters
// (r4: occupancy unchanged -> reg-file-limited at VGPR+AGPR~128 = 16 waves/CU cap),
// cvt_pk epilogues (r5: -3us), batched weight prefetch (r6: compiler re-sank),
// counter->extra-kernel (r7: -1us), 5-barrier X3full (r8: neutral),
// G/H conv1 split (r9: -18us, load-latency regime confirmed). ----------------
__global__ __launch_bounds__(256, 4)
void mlp_kernel(const float* __restrict__ G, const float* __restrict__ H,
                const float* __restrict__ w2, const float* __restrict__ b2,
                const float* __restrict__ w3, const float* __restrict__ b3,
                const float* __restrict__ fc1_b, const float* __restrict__ fc2_b,
                const float* __restrict__ fc3_b,
                const float* __restrict__ fc4_w, const float* __restrict__ fc4_b,
                const unsigned short* __restrict__ W1p, const unsigned short* __restrict__ W2p,
                const unsigned short* __restrict__ W3p,
                float* __restrict__ preds) {
    // LDS (floats): conv/fc1 phase: X1 at [0,512), X2 at [4096,8192).
    // fc3 phase: X3full spans [0,8192) — overwrites dead X1+X2 after fc2's reads.
    // part at [8192,8448).
    __shared__ __align__(16) float smem[8448];
    unsigned short* X1 = (unsigned short*)smem;
    unsigned short* X3f = (unsigned short*)smem;
    unsigned short* X2 = (unsigned short*)(smem + 4096);
    float* part = smem + 8192;

    const int tid = threadIdx.x;
    // XCD-aware swizzle: xcd = blockIdx.x % 8 owns contiguous work chunk of 512.
    const int bid = (blockIdx.x & 7) * 512 + (blockIdx.x >> 3);
    const int p = bid >> 2;
    const int e0 = (bid & 3) * 64;
    const int s = p >> 5, t = p & 31;
    if (s == t) return;

    const int lane = tid & 63, wave = tid >> 6;
    const int mrow = lane & 15, quad = lane >> 4;

    const int gsample = tid >> 2, o = tid & 3;  // conv roles
    float h1[23];
    // ---- conv1: G[p]+H[e] (bias pre-folded), pool THEN relu -> regs ----
    {
        const int e = e0 + gsample;
        const f32x4* Gp = (const f32x4*)(G + (p * 4 + o) * 48);
        const f32x4* Hp = (const f32x4*)(H + (e * 4 + o) * 48);
        float pre[46];
#pragma unroll
        for (int q = 0; q < 12; q++) {
            f32x4 x = Gp[q] + Hp[q];
#pragma unroll
            for (int z = 0; z < 4; z++) {
                int i = 4 * q + z;
                if (i < 46) pre[i] = x[z];
            }
        }
#pragma unroll
        for (int j = 0; j < 23; j++) h1[j] = fmaxf(fmaxf(pre[2 * j], pre[2 * j + 1]), 0.f);
    }
    float h2[10];
    // ---- conv2: cross-channel via DPP quad_perm, sliding ring; pool+relu fused ----
    {
        float wm[4][3];  // wm[m][k] = w2[o][o^m][k]
#pragma unroll
        for (int m = 0; m < 4; m++)
#pragma unroll
            for (int k = 0; k < 3; k++) wm[m][k] = w2[o * 12 + (o ^ m) * 3 + k];
        const float bb = b2[o];
        float win[4][3];
#pragma unroll
        for (int j = 0; j < 2; j++) {
            float x = h1[j];
            win[0][j] = x;
            win[1][j] = qp<0xB1>(x);
            win[2][j] = qp<0x4E>(x);
            win[3][j] = qp<0x1B>(x);
        }
        float pre[20];
#pragma unroll
        for (int i = 0; i < 20; i++) {
            float x = h1[i + 2];
            win[0][(i + 2) % 3] = x;
            win[1][(i + 2) % 3] = qp<0xB1>(x);
            win[2][(i + 2) % 3] = qp<0x4E>(x);
            win[3][(i + 2) % 3] = qp<0x1B>(x);
            float acc = bb;
#pragma unroll
            for (int m = 0; m < 4; m++)
#pragma unroll
                for (int k = 0; k < 3; k++)
                    acc = fmaf(wm[m][k], win[m][(i + k) % 3], acc);
            pre[i] = acc;
        }
#pragma unroll
        for (int j = 0; j < 10; j++) h2[j] = fmaxf(fmaxf(pre[2 * j], pre[2 * j + 1]), 0.f);
    }
    // ---- conv3; pool+relu fused; cvt_pk pack -> X1 (bf16 B-frag layout, K 16 pad 32) ----
    {
        float wm[4][3];
#pragma unroll
        for (int m = 0; m < 4; m++)
#pragma unroll
            for (int k = 0; k < 3; k++) wm[m][k] = w3[o * 12 + (o ^ m) * 3 + k];
        const float bb = b3[o];
        float win[4][3];
#pragma unroll
        for (int j = 0; j < 2; j++) {
            float x = h2[j];
            win[0][j] = x;
            win[1][j] = qp<0xB1>(x);
            win[2][j] = qp<0x4E>(x);
            win[3][j] = qp<0x1B>(x);
        }
        float pre[8];
#pragma unroll
        for (int i = 0; i < 8; i++) {
            float x = h2[i + 2];
            win[0][(i + 2) % 3] = x;
            win[1][(i + 2) % 3] = qp<0xB1>(x);
            win[2][(i + 2) % 3] = qp<0x4E>(x);
            win[3][(i + 2) % 3] = qp<0x1B>(x);
            float acc = bb;
#pragma unroll
            for (int m = 0; m < 4; m++)
#pragma unroll
                for (int k = 0; k < 3; k++)
                    acc = fmaf(wm[m][k], win[m][(i + k) % 3], acc);
            pre[i] = acc;
        }
        float v0 = fmaxf(fmaxf(pre[0], pre[1]), 0.f);
        float v1 = fmaxf(fmaxf(pre[2], pre[3]), 0.f);
        float v2 = fmaxf(fmaxf(pre[4], pre[5]), 0.f);
        float v3 = fmaxf(fmaxf(pre[6], pre[7]), 0.f);
        uint2v d;
        d.x = cvt_pk_bf16(v0, v1);
        d.y = cvt_pk_bf16(v2, v3);
        *(uint2v*)(X1 + (((o >> 1) * 64 + gsample) * 8) + (o & 1) * 4) = d;
        uint2v z2 = (uint2v){0u, 0u};  // k in [16,32) zeros
        *(uint2v*)(X1 + ((((o >> 1) + 2) * 64 + gsample) * 8) + (o & 1) * 4) = z2;
    }
    const short8* W1v = (const short8*)W1p;
    short8 w1f[2];
#pragma unroll
    for (int mtl = 0; mtl < 2; mtl++)
        w1f[mtl] = W1v[(wave * 2 + mtl) * 64 + lane];
    __syncthreads();  // barrier 1: X1 visible
    // ---- fc1 MFMA: A=w1f, B=X1; epilogue -> X2 ----
    {
        short8 bnt[4];
#pragma unroll
        for (int nt = 0; nt < 4; nt++)
            bnt[nt] = *(const short8*)(X1 + (quad * 64 + nt * 16 + mrow) * 8);
        f32x4 acc1[2][4];
#pragma unroll
        for (int a = 0; a < 2; a++)
#pragma unroll
            for (int b = 0; b < 4; b++) acc1[a][b] = (f32x4){0.f, 0.f, 0.f, 0.f};
#pragma unroll
        for (int mtl = 0; mtl < 2; mtl++) {
#pragma unroll
            for (int nt = 0; nt < 4; nt++)
                acc1[mtl][nt] = __builtin_amdgcn_mfma_f32_16x16x32_bf16(w1f[mtl], bnt[nt], acc1[mtl][nt], 0, 0, 0);
        }
#pragma unroll
        for (int mtl = 0; mtl < 2; mtl++) {
            const int mt = wave * 2 + mtl;
            const int n0 = mt * 16 + quad * 4;
            f32x4 b4 = *(const f32x4*)(fc1_b + n0);
#pragma unroll
            for (int nt = 0; nt < 4; nt++) {
                float x0 = fmaxf(acc1[mtl][nt][0] + b4[0], 0.f);
                float x1 = fmaxf(acc1[mtl][nt][1] + b4[1], 0.f);
                float x2 = fmaxf(acc1[mtl][nt][2] + b4[2], 0.f);
                float x3 = fmaxf(acc1[mtl][nt][3] + b4[3], 0.f);
                uint2v d;
                d.x = cvt_pk_bf16(x0, x1);
                d.y = cvt_pk_bf16(x2, x3);
                *(uint2v*)(X2 + ((n0 >> 3) * 64 + nt * 16 + mrow) * 8 + (n0 & 7)) = d;
            }
        }
    }
    __syncthreads();  // barrier 2: X2 ready
    // ---- fc2: full K=128, wave owns 4 of 16 mt (mt = q*4+wave), acc in regs ----
    const short8* W2v = (const short8*)W2p;
    const short8* W3v = (const short8*)W3p;
    f32x4 acc2[4][4];
#pragma unroll
    for (int a = 0; a < 4; a++)
#pragma unroll
        for (int b = 0; b < 4; b++) acc2[a][b] = (f32x4){0.f, 0.f, 0.f, 0.f};
#pragma unroll
    for (int ks = 0; ks < 4; ks++) {
        short8 bfr[4];
#pragma unroll
        for (int nt = 0; nt < 4; nt++)
            bfr[nt] = *(const short8*)(X2 + ((ks * 4 + quad) * 64 + nt * 16 + mrow) * 8);
#pragma unroll
        for (int q = 0; q < 4; q++) {
            const int mt = q * 4 + wave;
            short8 ah = W2v[(mt * 4 + ks) * 64 + lane];
#pragma unroll
            for (int nt = 0; nt < 4; nt++)
                acc2[q][nt] = __builtin_amdgcn_mfma_f32_16x16x32_bf16(ah, bfr[nt], acc2[q][nt], 0, 0, 0);
        }
    }
    __syncthreads();  // barrier 3: all X2 reads done; X1+X2 regions now dead
    // ---- fc2 epilogue -> X3full (32KB over [0,8192) floats) ----
#pragma unroll
    for (int q = 0; q < 4; q++) {
        const int mt = q * 4 + wave;
        const int n0 = mt * 16 + quad * 4;  // = k index in [0,256)
        f32x4 b4 = *(const f32x4*)(fc2_b + n0);
#pragma unroll
        for (int nt = 0; nt < 4; nt++) {
            float x0 = fmaxf(acc2[q][nt][0] + b4[0], 0.f);
            float x1 = fmaxf(acc2[q][nt][1] + b4[1], 0.f);
            float x2 = fmaxf(acc2[q][nt][2] + b4[2], 0.f);
            float x3 = fmaxf(acc2[q][nt][3] + b4[3], 0.f);
            uint2v d;
            d.x = cvt_pk_bf16(x0, x1);
            d.y = cvt_pk_bf16(x2, x3);
            *(uint2v*)(X3f + ((n0 >> 3) * 64 + nt * 16 + mrow) * 8 + (n0 & 7)) = d;
        }
    }
    __syncthreads();  // barrier 4: X3full ready
    // ---- fc3: all 8 k-steps uninterrupted ----
    f32x4 acc3[2][4];
#pragma unroll
    for (int a = 0; a < 2; a++)
#pragma unroll
        for (int b = 0; b < 4; b++) acc3[a][b] = (f32x4){0.f, 0.f, 0.f, 0.f};
#pragma unroll
    for (int ks = 0; ks < 8; ks++) {
        short8 bfr[4];
#pragma unroll
        for (int nt = 0; nt < 4; nt++)
            bfr[nt] = *(const short8*)(X3f + ((ks * 4 + quad) * 64 + nt * 16 + mrow) * 8);
#pragma unroll
        for (int mtl = 0; mtl < 2; mtl++) {
            const int mt = wave * 2 + mtl;
            short8 ah = W3v[(mt * 8 + ks) * 64 + lane];
#pragma unroll
            for (int nt = 0; nt < 4; nt++)
                acc3[mtl][nt] = __builtin_amdgcn_mfma_f32_16x16x32_bf16(ah, bfr[nt], acc3[mtl][nt], 0, 0, 0);
        }
    }
    // ---- fused fc4 ----
    {
        float p4[4] = {0.f, 0.f, 0.f, 0.f};
#pragma unroll
        for (int mtl = 0; mtl < 2; mtl++) {
            const int mt = wave * 2 + mtl;
            const int n0 = mt * 16 + quad * 4;
            f32x4 b4 = *(const f32x4*)(fc3_b + n0);
            f32x4 w44 = *(const f32x4*)(fc4_w + n0);
#pragma unroll
            for (int nt = 0; nt < 4; nt++)
#pragma unroll
                for (int r = 0; r < 4; r++)
                    p4[nt] = fmaf(fmaxf(acc3[mtl][nt][r] + b4[r], 0.f), w44[r], p4[nt]);
        }
#pragma unroll
        for (int nt = 0; nt < 4; nt++) {
            p4[nt] += __shfl_xor(p4[nt], 16, 64);
            p4[nt] += __shfl_xor(p4[nt], 32, 64);
        }
        if (quad == 0) {
#pragma unroll
            for (int nt = 0; nt < 4; nt++)
                part[wave * 64 + nt * 16 + mrow] = p4[nt];
        }
    }
    __syncthreads();  // barrier 5: part ready
    if (tid < 64) {
        float pred = part[tid] + part[64 + tid] + part[128 + tid] + part[192 + tid] + fc4_b[0];
        preds[p * 256 + e0 + tid] = pred;
    }
}

// ---------------- Kernel 2: propagation only, one WAVE per pair (256 blocks). ----------------
__global__ __launch_bounds__(256)
void prop_kernel(const int* __restrict__ edges, const float* __restrict__ preds,
                 float* __restrict__ rbc_part) {
    const int tid = threadIdx.x;
    const int wave = tid >> 6, lane = tid & 63;
    const int p = blockIdx.x * 4 + wave;
    const int s = p >> 5, t = p & 31;
    __shared__ float xw[4][32], xnw[4][32], raccw[4][32];
    int u[4], v[4];
    float pr[4];
#pragma unroll
    for (int j = 0; j < 4; j++) {
        int e = lane + 64 * j;
        u[j] = edges[2 * e];
        v[j] = edges[2 * e + 1];
        pr[j] = preds[p * 256 + e];
    }
    if (lane < 32) { xw[wave][lane] = (lane == s) ? 1.f : 0.f; raccw[wave][lane] = 0.f; }
    const bool active = (s != t);
    for (int step = 0; step < 3; step++) {
        if (lane < 32) xnw[wave][lane] = 0.f;
        __syncthreads();
        if (active) {
#pragma unroll
            for (int j = 0; j < 4; j++)
                atomicAdd(&xnw[wave][v[j]], xw[wave][u[j]] * pr[j]);
        }
        __syncthreads();
        if (lane < 32) { raccw[wave][lane] += xnw[wave][lane]; xw[wave][lane] = xnw[wave][lane]; }
        __syncthreads();
    }
    if (active && lane < 32) atomicAdd(&rbc_part[(p & 63) * 32 + lane], raccw[wave][lane]);
}

// ---------------- Kernel 3: final reduce + normalize (1 block). ----------------
__global__ __launch_bounds__(256)
void norm_kernel(const float* __restrict__ rbc_part, float* __restrict__ out) {
    const int tid = threadIdx.x;
    const int node = tid & 31, sub = tid >> 5;
    __shared__ float red[8][32];
    float vv = 0.f;
#pragma unroll
    for (int g = 0; g < 8; g++)
        vv += rbc_part[(sub * 8 + g) * 32 + node];
    red[sub][node] = vv;
    __syncthreads();
    if (tid < 32) {
        float acc = 0.f;
#pragma unroll
        for (int sb = 0; sb < 8; sb++) acc += red[sb][tid];
        float tot = acc;
#pragma unroll
        for (int mask = 1; mask < 32; mask <<= 1) tot += __shfl_xor(tot, mask, 32);
        out[tid] = acc / tot;
    }
}

extern "C" void kernel_launch(void* const* d_in, const int* in_sizes, int n_in,
                              void* d_out, int out_size, void* d_ws, size_t ws_size,
                              hipStream_t stream) {
    const float* emb = (const float*)d_in[0];
    const int* edges = (const int*)d_in[1];
    const float* w1 = (const float*)d_in[2];
    const float* b1 = (const float*)d_in[3];
    const float* w2 = (const float*)d_in[4];
    const float* b2 = (const float*)d_in[5];
    const float* w3 = (const float*)d_in[6];
    const float* b3 = (const float*)d_in[7];
    const float* fc1_w = (const float*)d_in[8];
    const float* fc1_b = (const float*)d_in[9];
    const float* fc2_w = (const float*)d_in[10];
    const float* fc2_b = (const float*)d_in[11];
    const float* fc3_w = (const float*)d_in[12];
    const float* fc3_b = (const float*)d_in[13];
    const float* fc4_w = (const float*)d_in[14];
    const float* fc4_b = (const float*)d_in[15];

    float* ws = (float*)d_ws;
    float* G = ws + G_OFF;
    float* H = ws + H_OFF;
    float* preds = ws + PREDS_OFF;
    float* rbc_part = ws + RBCP_OFF;
    unsigned short* W1p = (unsigned short*)(ws + W1P_OFF);
    unsigned short* W2p = (unsigned short*)(ws + W2P_OFF);
    unsigned short* W3p = (unsigned short*)(ws + W3P_OFF);
    float* out = (float*)d_out;

    prep_all<<<dim3(1233), dim3(256), 0, stream>>>(emb, edges, w1, b1, fc1_w, fc2_w, fc3_w,
                                                   G, H, W1p, W2p, W3p, rbc_part);
    mlp_kernel<<<dim3(4096), dim3(256), 0, stream>>>(
        G, H, w2, b2, w3, b3, fc1_b, fc2_b, fc3_b,
        fc4_w, fc4_b, W1p, W2p, W3p, preds);
    prop_kernel<<<dim3(256), dim3(256), 0, stream>>>(edges, preds, rbc_part);
    norm_kernel<<<dim3(1), dim3(256), 0, stream>>>(rbc_part, out);
}